// Round 6
// baseline (166.301 us; speedup 1.0000x reference)
//
#include <hip/hip_runtime.h>

// Pipeline (fp16-packed gathers, fp32 math, MFMA node-GEMM, dst-sorted attention):
//   k_transpose : W1 fp32 -> W1^T bf16, pre-swizzled byte image
//   k_gemm : g = h@W1 via mfma_f32_16x16x32_bf16; emits hh = fp16x2 copy of h
//   k_hist/scanA/B/C/fill0 : dst-CSR; bsrc[i] = src of i-th dst-sorted edge
//   k_att2 : wave per dst; d-row in regs; per edge gather gh[s] only;
//            bucket[i]=(s,att); denom[s]+=att
//   k_w    : bucket[i].y = att/denom[s]
//   k_agg  : wave per dst, 4 sub-groups x 16 lanes; out[d]=sum w*hh[s]

typedef unsigned int uint;
typedef unsigned short ushort;
typedef __attribute__((ext_vector_type(8))) short short8;
typedef __attribute__((ext_vector_type(4))) float f32x4;

static __device__ __forceinline__ uint pack_f16(float a, float b) {
  _Float16 ha = (_Float16)a, hb = (_Float16)b;
  unsigned short ua = __builtin_bit_cast(unsigned short, ha);
  unsigned short ub = __builtin_bit_cast(unsigned short, hb);
  return ((uint)ub << 16) | ua;
}
static __device__ __forceinline__ float2 unpack_f16(uint u) {
  _Float16 lo = __builtin_bit_cast(_Float16, (unsigned short)(u & 0xffffu));
  _Float16 hi = __builtin_bit_cast(_Float16, (unsigned short)(u >> 16));
  return make_float2((float)lo, (float)hi);
}
static __device__ __forceinline__ ushort f2bf(float x) {
  uint u = __float_as_uint(x);
  u += 0x7fffu + ((u >> 16) & 1u);   // RNE
  return (ushort)(u >> 16);
}

__global__ __launch_bounds__(256) void k_transpose(const float* __restrict__ W1,
                                                   ushort* __restrict__ w1t_swz) {
  int idx = blockIdx.x * 256 + threadIdx.x;   // 64 blocks -> 16384
  int n = idx >> 7, k = idx & 127;
  float v = W1[k * 128 + n];
  int byte_off = n * 256 + ((k * 2) ^ ((n & 7) << 4));
  w1t_swz[byte_off >> 1] = f2bf(v);
}

__global__ __launch_bounds__(256) void k_gemm(const float* __restrict__ h,
                                              const ushort* __restrict__ w1t_swz,
                                              uint* __restrict__ gh,
                                              uint4* __restrict__ hh4,
                                              int n_nodes) {
  __shared__ ushort w1s[16384];   // 32 KiB swizzled W1^T image
  int tid = threadIdx.x;
  {
    const uint4* srcw = (const uint4*)w1t_swz;
    uint4* dstw = (uint4*)w1s;
    #pragma unroll
    for (int i = 0; i < 8; ++i) dstw[tid + 256 * i] = srcw[tid + 256 * i];
  }
  __syncthreads();
  int wave = tid >> 6, lane = tid & 63;
  int tile = blockIdx.x * 4 + wave;
  if (tile * 16 >= n_nodes) return;
  int n0 = tile * 16;
  int l15 = lane & 15, kq = lane >> 4;
  int row = n0 + l15;

  f32x4 acc[8];
  #pragma unroll
  for (int ct = 0; ct < 8; ++ct) acc[ct] = (f32x4){0.f, 0.f, 0.f, 0.f};

  #pragma unroll
  for (int kb = 0; kb < 4; ++kb) {
    const float* hp = &h[(size_t)row * 128 + kb * 32 + kq * 8];
    float4 p0 = *(const float4*)hp;
    float4 p1 = *(const float4*)(hp + 4);
    short8 a;
    a[0] = (short)f2bf(p0.x); a[1] = (short)f2bf(p0.y);
    a[2] = (short)f2bf(p0.z); a[3] = (short)f2bf(p0.w);
    a[4] = (short)f2bf(p1.x); a[5] = (short)f2bf(p1.y);
    a[6] = (short)f2bf(p1.z); a[7] = (short)f2bf(p1.w);
    uint4 hv;
    hv.x = pack_f16(p0.x, p0.y); hv.y = pack_f16(p0.z, p0.w);
    hv.z = pack_f16(p1.x, p1.y); hv.w = pack_f16(p1.z, p1.w);
    hh4[(size_t)row * 16 + kb * 4 + kq] = hv;
    #pragma unroll
    for (int ct = 0; ct < 8; ++ct) {
      int n = ct * 16 + l15;
      int byte_off = n * 256 + (((kb * 64) + kq * 16) ^ ((n & 7) << 4));
      short8 b = *(const short8*)((const char*)w1s + byte_off);
      acc[ct] = __builtin_amdgcn_mfma_f32_16x16x32_bf16(a, b, acc[ct], 0, 0, 0);
    }
  }
  ushort* gh16 = (ushort*)gh;
  #pragma unroll
  for (int ct = 0; ct < 8; ++ct) {
    #pragma unroll
    for (int r = 0; r < 4; ++r) {
      int orow = n0 + kq * 4 + r;
      _Float16 v = (_Float16)acc[ct][r];
      gh16[(size_t)orow * 128 + ct * 16 + l15] = __builtin_bit_cast(unsigned short, v);
    }
  }
}

__global__ __launch_bounds__(256) void k_hist(const int* __restrict__ dst,
                                              int* __restrict__ counts, int n_edges) {
  int i = blockIdx.x * blockDim.x + threadIdx.x;
  int stride = gridDim.x * blockDim.x;
  for (int e = i; e < n_edges; e += stride) atomicAdd(&counts[dst[e]], 1);
}

__global__ __launch_bounds__(256) void k_scanA(const int* __restrict__ counts,
                                               int* __restrict__ partials,
                                               int n, int chunk) {
  __shared__ int red[256];
  int b = blockIdx.x, t = threadIdx.x;
  int idx = b * chunk + t;
  red[t] = (t < chunk && idx < n) ? counts[idx] : 0;
  __syncthreads();
  for (int off = 128; off > 0; off >>= 1) {
    if (t < off) red[t] += red[t + off];
    __syncthreads();
  }
  if (t == 0) partials[b] = red[0];
}

__global__ __launch_bounds__(256) void k_scanB(int* __restrict__ partials,
                                               int* __restrict__ row_start,
                                               int n, int total) {
  __shared__ int p[256];
  int t = threadIdx.x;
  int orig = partials[t];
  p[t] = orig;
  __syncthreads();
  #pragma unroll
  for (int off = 1; off < 256; off <<= 1) {
    int v = (t >= off) ? p[t - off] : 0;
    __syncthreads();
    p[t] += v;
    __syncthreads();
  }
  partials[t] = p[t] - orig;
  if (t == 0) row_start[n] = total;
}

__global__ __launch_bounds__(256) void k_scanC(int* __restrict__ counts,
                                               const int* __restrict__ partials,
                                               int* __restrict__ row_start,
                                               int n, int chunk) {
  __shared__ int p[256];
  int b = blockIdx.x, t = threadIdx.x;
  int idx = b * chunk + t;
  bool ok = (t < chunk && idx < n);
  int orig = ok ? counts[idx] : 0;
  p[t] = orig;
  __syncthreads();
  #pragma unroll
  for (int off = 1; off < 256; off <<= 1) {
    int v = (t >= off) ? p[t - off] : 0;
    __syncthreads();
    p[t] += v;
    __syncthreads();
  }
  if (ok) {
    row_start[idx] = partials[b] + p[t] - orig;
    counts[idx] = 0;  // becomes cursor for k_fill0
  }
}

__global__ __launch_bounds__(256) void k_fill0(const int* __restrict__ src,
                                               const int* __restrict__ dst,
                                               const int* __restrict__ row_start,
                                               int* __restrict__ cursor,
                                               int* __restrict__ bsrc,
                                               int n_edges) {
  int i = blockIdx.x * blockDim.x + threadIdx.x;
  int stride = gridDim.x * blockDim.x;
  for (int e = i; e < n_edges; e += stride) {
    int d = dst[e];
    int pos = atomicAdd(&cursor[d], 1);
    bsrc[row_start[d] + pos] = src[e];
  }
}

// wave per dst: d-row cached in registers; one random gather (gh[s]) per edge
__global__ __launch_bounds__(256) void k_att2(const uint4* __restrict__ gh4,
                                              const int* __restrict__ bsrc,
                                              const int* __restrict__ row_start,
                                              const float* __restrict__ b1,
                                              const float* __restrict__ W2,
                                              const float* __restrict__ b2,
                                              int2* __restrict__ bucket,
                                              float* __restrict__ denom,
                                              int n_nodes) {
  int lane = threadIdx.x & 63;
  int sub = lane >> 4, l16 = lane & 15;
  int d = blockIdx.x * 4 + (threadIdx.x >> 6);
  if (d >= n_nodes) return;
  int beg = row_start[d], end = row_start[d + 1];
  if (beg == end) return;
  float4 b1a = *(const float4*)&b1[l16 * 8];
  float4 b1b = *(const float4*)&b1[l16 * 8 + 4];
  float4 w2a = *(const float4*)&W2[l16 * 8];
  float4 w2b = *(const float4*)&W2[l16 * 8 + 4];
  float b2v = b2[0];
  uint4 ud = gh4[(size_t)d * 16 + l16];
  float2 d0 = unpack_f16(ud.x), d1 = unpack_f16(ud.y);
  float2 d2 = unpack_f16(ud.z), d3 = unpack_f16(ud.w);
  float c0 = b1a.x - d0.x, c1 = b1a.y - d0.y, c2 = b1a.z - d1.x, c3 = b1a.w - d1.y;
  float c4 = b1b.x - d2.x, c5 = b1b.y - d2.y, c6 = b1b.z - d3.x, c7 = b1b.w - d3.y;
  for (int jb = beg; jb < end; jb += 4) {
    int j = jb + sub;
    bool valid = j < end;
    int s = 0;
    float acc = 0.f;
    if (valid) {
      s = bsrc[j];
      uint4 us = gh4[(size_t)s * 16 + l16];
      float2 s0 = unpack_f16(us.x), s1 = unpack_f16(us.y);
      float2 s2 = unpack_f16(us.z), s3 = unpack_f16(us.w);
      float t;
      t = fmaxf(s0.x + c0, 0.f); acc = fmaf(t, w2a.x, acc);
      t = fmaxf(s0.y + c1, 0.f); acc = fmaf(t, w2a.y, acc);
      t = fmaxf(s1.x + c2, 0.f); acc = fmaf(t, w2a.z, acc);
      t = fmaxf(s1.y + c3, 0.f); acc = fmaf(t, w2a.w, acc);
      t = fmaxf(s2.x + c4, 0.f); acc = fmaf(t, w2b.x, acc);
      t = fmaxf(s2.y + c5, 0.f); acc = fmaf(t, w2b.y, acc);
      t = fmaxf(s3.x + c6, 0.f); acc = fmaf(t, w2b.z, acc);
      t = fmaxf(s3.y + c7, 0.f); acc = fmaf(t, w2b.w, acc);
    }
    acc += __shfl_xor(acc, 1);
    acc += __shfl_xor(acc, 2);
    acc += __shfl_xor(acc, 4);
    acc += __shfl_xor(acc, 8);
    if (l16 == 0 && valid) {
      float a = fmaxf(acc + b2v, 0.f);
      a = 1.f / (1.f + __expf(-a));
      bucket[j] = make_int2(s, __float_as_int(a));
      atomicAdd(&denom[s], a);
    }
  }
}

__global__ __launch_bounds__(256) void k_w(int2* __restrict__ bucket,
                                           const float* __restrict__ denom,
                                           int n_edges) {
  int i = blockIdx.x * blockDim.x + threadIdx.x;
  int stride = gridDim.x * blockDim.x;
  for (; i < n_edges; i += stride) {
    int2 e = bucket[i];
    float w = __int_as_float(e.y) / denom[e.x];
    bucket[i] = make_int2(e.x, __float_as_int(w));
  }
}

__global__ __launch_bounds__(256) void k_agg(const uint4* __restrict__ hh4,
                                             const int* __restrict__ row_start,
                                             const int2* __restrict__ bucket,
                                             float* __restrict__ out, int n_nodes) {
  int lane = threadIdx.x & 63;
  int sub = lane >> 4, l16 = lane & 15;
  int d = blockIdx.x * 4 + (threadIdx.x >> 6);
  if (d >= n_nodes) return;
  int beg = row_start[d], end = row_start[d + 1];
  int cnt = end - beg;
  float a0 = 0.f, a1 = 0.f, a2 = 0.f, a3 = 0.f;
  float a4 = 0.f, a5 = 0.f, a6 = 0.f, a7 = 0.f;
  for (int base = 0; base < cnt; base += 64) {
    int nb = cnt - base; if (nb > 64) nb = 64;
    int2 ew = make_int2(0, 0);
    if (lane < nb) ew = bucket[beg + base + lane];
    int steps = (nb + 3) >> 2;
    for (int j = 0; j < steps; ++j) {
      int idx = j * 4 + sub;
      int s = __shfl(ew.x, idx);
      float w = __int_as_float(__shfl(ew.y, idx));
      if (idx < nb) {
        uint4 v = hh4[(size_t)s * 16 + l16];
        float2 f0 = unpack_f16(v.x), f1 = unpack_f16(v.y);
        float2 f2 = unpack_f16(v.z), f3 = unpack_f16(v.w);
        a0 = fmaf(w, f0.x, a0); a1 = fmaf(w, f0.y, a1);
        a2 = fmaf(w, f1.x, a2); a3 = fmaf(w, f1.y, a3);
        a4 = fmaf(w, f2.x, a4); a5 = fmaf(w, f2.y, a5);
        a6 = fmaf(w, f3.x, a6); a7 = fmaf(w, f3.y, a7);
      }
    }
  }
  #pragma unroll
  for (int off = 16; off < 64; off <<= 1) {
    a0 += __shfl_xor(a0, off); a1 += __shfl_xor(a1, off);
    a2 += __shfl_xor(a2, off); a3 += __shfl_xor(a3, off);
    a4 += __shfl_xor(a4, off); a5 += __shfl_xor(a5, off);
    a6 += __shfl_xor(a6, off); a7 += __shfl_xor(a7, off);
  }
  if (sub == 0) {
    *(float4*)&out[(size_t)d * 128 + l16 * 8]     = make_float4(a0, a1, a2, a3);
    *(float4*)&out[(size_t)d * 128 + l16 * 8 + 4] = make_float4(a4, a5, a6, a7);
  }
}

extern "C" void kernel_launch(void* const* d_in, const int* in_sizes, int n_in,
                              void* d_out, int out_size, void* d_ws, size_t ws_size,
                              hipStream_t stream) {
  const float* h   = (const float*)d_in[0];
  const int*   src = (const int*)d_in[1];
  const int*   dst = (const int*)d_in[2];
  const float* W1  = (const float*)d_in[3];
  const float* b1  = (const float*)d_in[4];
  const float* W2  = (const float*)d_in[5];
  const float* b2  = (const float*)d_in[6];
  float* out = (float*)d_out;

  int n_nodes = in_sizes[0] / 128;
  int n_edges = in_sizes[1];

  char* ws = (char*)d_ws;
  uint*   gh        = (uint*)ws;                            // n*64
  uint*   hh        = gh + (size_t)n_nodes * 64;            // n*64
  float*  denom     = (float*)(hh + (size_t)n_nodes * 64);  // n
  int*    counts    = (int*)(denom + n_nodes);              // n (cursor later)
  int*    row_start = counts + n_nodes;                     // n+1
  int*    partials  = row_start + n_nodes + 1;              // 256
  ushort* w1t       = (ushort*)(partials + 256);            // 16384 (32 KiB)
  int*    bsrc      = (int*)(w1t + 16384);                  // E
  int2*   bucket    = (int2*)(((uintptr_t)(bsrc + n_edges) + 15) & ~(uintptr_t)15);

  hipMemsetAsync(denom, 0, (size_t)2 * n_nodes * sizeof(float), stream);

  int chunk = (n_nodes + 255) / 256;
  int n_tiles = (n_nodes + 15) / 16;
  int nblk4 = (n_nodes + 3) / 4;
  k_transpose<<<64, 256, 0, stream>>>(W1, w1t);
  k_gemm <<<(n_tiles + 3) / 4, 256, 0, stream>>>(h, w1t, gh, (uint4*)hh, n_nodes);
  k_hist <<<1024, 256, 0, stream>>>(dst, counts, n_edges);
  k_scanA<<<256, 256, 0, stream>>>(counts, partials, n_nodes, chunk);
  k_scanB<<<1, 256, 0, stream>>>(partials, row_start, n_nodes, n_edges);
  k_scanC<<<256, 256, 0, stream>>>(counts, partials, row_start, n_nodes, chunk);
  k_fill0<<<1024, 256, 0, stream>>>(src, dst, row_start, counts, bsrc, n_edges);
  k_att2 <<<nblk4, 256, 0, stream>>>((const uint4*)gh, bsrc, row_start, b1, W2, b2,
                                     bucket, denom, n_nodes);
  k_w    <<<1024, 256, 0, stream>>>(bucket, denom, n_edges);
  k_agg  <<<nblk4, 256, 0, stream>>>((const uint4*)hh, row_start, bucket, out, n_nodes);
}

// Round 7
// 159.304 us; speedup vs baseline: 1.0439x; 1.0439x over previous
//
#include <hip/hip_runtime.h>

// Pipeline (fp16-packed gathers, fp32 math, MFMA node-GEMM, dst-sorted attention):
//   k_misc : blocks<64: W1 -> W1^T bf16 pre-swizzled; blocks>=64: hist counts[dst]++
//   k_gemm : g = h@W1 via mfma_f32_16x16x32_bf16; emits hh = fp16x2 copy of h
//   scanA/B/C : exclusive scan counts -> row_start; zero counts (cursor)
//   k_fill0: bsrc[i] = src of i-th dst-sorted edge
//   k_att2 : wave per dst; d-row in regs; 1 gather/edge; pk-f16 + fdot2 math;
//            bucket[i]=(s,att); denom[s]+=att
//   k_agg  : wave per dst; lane loading bucket divides att/denom[s]; out[d]=sum w*hh[s]

typedef unsigned int uint;
typedef unsigned short ushort;
typedef __attribute__((ext_vector_type(8))) short short8;
typedef __attribute__((ext_vector_type(4))) float f32x4;
typedef __attribute__((ext_vector_type(2))) _Float16 h2;

static __device__ __forceinline__ uint pack_f16(float a, float b) {
  _Float16 ha = (_Float16)a, hb = (_Float16)b;
  unsigned short ua = __builtin_bit_cast(unsigned short, ha);
  unsigned short ub = __builtin_bit_cast(unsigned short, hb);
  return ((uint)ub << 16) | ua;
}
static __device__ __forceinline__ float2 unpack_f16(uint u) {
  _Float16 lo = __builtin_bit_cast(_Float16, (unsigned short)(u & 0xffffu));
  _Float16 hi = __builtin_bit_cast(_Float16, (unsigned short)(u >> 16));
  return make_float2((float)lo, (float)hi);
}
static __device__ __forceinline__ h2 as_h2(uint u) { return __builtin_bit_cast(h2, u); }
static __device__ __forceinline__ h2 relu2(h2 a) {
  h2 r;
  r.x = a.x > (_Float16)0 ? a.x : (_Float16)0;
  r.y = a.y > (_Float16)0 ? a.y : (_Float16)0;
  return r;
}
static __device__ __forceinline__ float dot2acc(h2 a, h2 b, float c) {
#if __has_builtin(__builtin_amdgcn_fdot2)
  return __builtin_amdgcn_fdot2(a, b, c, false);
#else
  return c + (float)a.x * (float)b.x + (float)a.y * (float)b.y;
#endif
}
static __device__ __forceinline__ ushort f2bf(float x) {
  uint u = __float_as_uint(x);
  u += 0x7fffu + ((u >> 16) & 1u);   // RNE
  return (ushort)(u >> 16);
}

// blocks 0..63: W1[k][n] fp32 -> W1^T bf16 swizzled; blocks 64+: counts[dst[e]]++
__global__ __launch_bounds__(256) void k_misc(const float* __restrict__ W1,
                                              ushort* __restrict__ w1t_swz,
                                              const int* __restrict__ dst,
                                              int* __restrict__ counts, int n_edges) {
  int b = blockIdx.x;
  if (b < 64) {
    int idx = b * 256 + threadIdx.x;
    int n = idx >> 7, k = idx & 127;
    float v = W1[k * 128 + n];
    int byte_off = n * 256 + ((k * 2) ^ ((n & 7) << 4));
    w1t_swz[byte_off >> 1] = f2bf(v);
  } else {
    int i = (b - 64) * 256 + threadIdx.x;
    int stride = (gridDim.x - 64) * 256;
    for (int e = i; e < n_edges; e += stride) atomicAdd(&counts[dst[e]], 1);
  }
}

__global__ __launch_bounds__(256) void k_gemm(const float* __restrict__ h,
                                              const ushort* __restrict__ w1t_swz,
                                              uint* __restrict__ gh,
                                              uint4* __restrict__ hh4,
                                              int n_nodes) {
  __shared__ ushort w1s[16384];   // 32 KiB swizzled W1^T image
  int tid = threadIdx.x;
  {
    const uint4* srcw = (const uint4*)w1t_swz;
    uint4* dstw = (uint4*)w1s;
    #pragma unroll
    for (int i = 0; i < 8; ++i) dstw[tid + 256 * i] = srcw[tid + 256 * i];
  }
  __syncthreads();
  int wave = tid >> 6, lane = tid & 63;
  int tile = blockIdx.x * 4 + wave;
  if (tile * 16 >= n_nodes) return;
  int n0 = tile * 16;
  int l15 = lane & 15, kq = lane >> 4;
  int row = n0 + l15;

  f32x4 acc[8];
  #pragma unroll
  for (int ct = 0; ct < 8; ++ct) acc[ct] = (f32x4){0.f, 0.f, 0.f, 0.f};

  #pragma unroll
  for (int kb = 0; kb < 4; ++kb) {
    const float* hp = &h[(size_t)row * 128 + kb * 32 + kq * 8];
    float4 p0 = *(const float4*)hp;
    float4 p1 = *(const float4*)(hp + 4);
    short8 a;
    a[0] = (short)f2bf(p0.x); a[1] = (short)f2bf(p0.y);
    a[2] = (short)f2bf(p0.z); a[3] = (short)f2bf(p0.w);
    a[4] = (short)f2bf(p1.x); a[5] = (short)f2bf(p1.y);
    a[6] = (short)f2bf(p1.z); a[7] = (short)f2bf(p1.w);
    uint4 hv;
    hv.x = pack_f16(p0.x, p0.y); hv.y = pack_f16(p0.z, p0.w);
    hv.z = pack_f16(p1.x, p1.y); hv.w = pack_f16(p1.z, p1.w);
    hh4[(size_t)row * 16 + kb * 4 + kq] = hv;
    #pragma unroll
    for (int ct = 0; ct < 8; ++ct) {
      int n = ct * 16 + l15;
      int byte_off = n * 256 + (((kb * 64) + kq * 16) ^ ((n & 7) << 4));
      short8 b = *(const short8*)((const char*)w1s + byte_off);
      acc[ct] = __builtin_amdgcn_mfma_f32_16x16x32_bf16(a, b, acc[ct], 0, 0, 0);
    }
  }
  ushort* gh16 = (ushort*)gh;
  #pragma unroll
  for (int ct = 0; ct < 8; ++ct) {
    #pragma unroll
    for (int r = 0; r < 4; ++r) {
      int orow = n0 + kq * 4 + r;
      _Float16 v = (_Float16)acc[ct][r];
      gh16[(size_t)orow * 128 + ct * 16 + l15] = __builtin_bit_cast(unsigned short, v);
    }
  }
}

__global__ __launch_bounds__(256) void k_scanA(const int* __restrict__ counts,
                                               int* __restrict__ partials,
                                               int n, int chunk) {
  __shared__ int red[256];
  int b = blockIdx.x, t = threadIdx.x;
  int idx = b * chunk + t;
  red[t] = (t < chunk && idx < n) ? counts[idx] : 0;
  __syncthreads();
  for (int off = 128; off > 0; off >>= 1) {
    if (t < off) red[t] += red[t + off];
    __syncthreads();
  }
  if (t == 0) partials[b] = red[0];
}

__global__ __launch_bounds__(256) void k_scanB(int* __restrict__ partials,
                                               int* __restrict__ row_start,
                                               int n, int total) {
  __shared__ int p[256];
  int t = threadIdx.x;
  int orig = partials[t];
  p[t] = orig;
  __syncthreads();
  #pragma unroll
  for (int off = 1; off < 256; off <<= 1) {
    int v = (t >= off) ? p[t - off] : 0;
    __syncthreads();
    p[t] += v;
    __syncthreads();
  }
  partials[t] = p[t] - orig;
  if (t == 0) row_start[n] = total;
}

__global__ __launch_bounds__(256) void k_scanC(int* __restrict__ counts,
                                               const int* __restrict__ partials,
                                               int* __restrict__ row_start,
                                               int n, int chunk) {
  __shared__ int p[256];
  int b = blockIdx.x, t = threadIdx.x;
  int idx = b * chunk + t;
  bool ok = (t < chunk && idx < n);
  int orig = ok ? counts[idx] : 0;
  p[t] = orig;
  __syncthreads();
  #pragma unroll
  for (int off = 1; off < 256; off <<= 1) {
    int v = (t >= off) ? p[t - off] : 0;
    __syncthreads();
    p[t] += v;
    __syncthreads();
  }
  if (ok) {
    row_start[idx] = partials[b] + p[t] - orig;
    counts[idx] = 0;  // becomes cursor for k_fill0
  }
}

__global__ __launch_bounds__(256) void k_fill0(const int* __restrict__ src,
                                               const int* __restrict__ dst,
                                               const int* __restrict__ row_start,
                                               int* __restrict__ cursor,
                                               int* __restrict__ bsrc,
                                               int n_edges) {
  int i = blockIdx.x * blockDim.x + threadIdx.x;
  int stride = gridDim.x * blockDim.x;
  for (int e = i; e < n_edges; e += stride) {
    int d = dst[e];
    int pos = atomicAdd(&cursor[d], 1);
    bsrc[row_start[d] + pos] = src[e];
  }
}

// wave per dst: d-row cached in regs; 1 random gather/edge; pk-f16 + fdot2 math
__global__ __launch_bounds__(256) void k_att2(const uint4* __restrict__ gh4,
                                              const int* __restrict__ bsrc,
                                              const int* __restrict__ row_start,
                                              const float* __restrict__ b1,
                                              const float* __restrict__ W2,
                                              const float* __restrict__ b2,
                                              int2* __restrict__ bucket,
                                              float* __restrict__ denom,
                                              int n_nodes) {
  int lane = threadIdx.x & 63;
  int sub = lane >> 4, l16 = lane & 15;
  int d = blockIdx.x * 4 + (threadIdx.x >> 6);
  if (d >= n_nodes) return;
  int beg = row_start[d], end = row_start[d + 1];
  if (beg == end) return;
  float4 b1a = *(const float4*)&b1[l16 * 8];
  float4 b1b = *(const float4*)&b1[l16 * 8 + 4];
  float4 w2a = *(const float4*)&W2[l16 * 8];
  float4 w2b = *(const float4*)&W2[l16 * 8 + 4];
  float b2v = b2[0];
  uint4 ud = gh4[(size_t)d * 16 + l16];
  float2 d0 = unpack_f16(ud.x), d1 = unpack_f16(ud.y);
  float2 d2 = unpack_f16(ud.z), d3 = unpack_f16(ud.w);
  h2 c0, c1, c2, c3, wh0, wh1, wh2, wh3;
  c0.x = (_Float16)(b1a.x - d0.x); c0.y = (_Float16)(b1a.y - d0.y);
  c1.x = (_Float16)(b1a.z - d1.x); c1.y = (_Float16)(b1a.w - d1.y);
  c2.x = (_Float16)(b1b.x - d2.x); c2.y = (_Float16)(b1b.y - d2.y);
  c3.x = (_Float16)(b1b.z - d3.x); c3.y = (_Float16)(b1b.w - d3.y);
  wh0.x = (_Float16)w2a.x; wh0.y = (_Float16)w2a.y;
  wh1.x = (_Float16)w2a.z; wh1.y = (_Float16)w2a.w;
  wh2.x = (_Float16)w2b.x; wh2.y = (_Float16)w2b.y;
  wh3.x = (_Float16)w2b.z; wh3.y = (_Float16)w2b.w;
  for (int jb = beg; jb < end; jb += 4) {
    int j = jb + sub;
    bool valid = j < end;
    int s = 0;
    float acc = 0.f;
    if (valid) {
      s = bsrc[j];
      uint4 us = gh4[(size_t)s * 16 + l16];
      acc = dot2acc(relu2(as_h2(us.x) + c0), wh0, acc);
      acc = dot2acc(relu2(as_h2(us.y) + c1), wh1, acc);
      acc = dot2acc(relu2(as_h2(us.z) + c2), wh2, acc);
      acc = dot2acc(relu2(as_h2(us.w) + c3), wh3, acc);
    }
    acc += __shfl_xor(acc, 1);
    acc += __shfl_xor(acc, 2);
    acc += __shfl_xor(acc, 4);
    acc += __shfl_xor(acc, 8);
    if (l16 == 0 && valid) {
      float a = fmaxf(acc + b2v, 0.f);
      a = 1.f / (1.f + __expf(-a));
      bucket[j] = make_int2(s, __float_as_int(a));
      atomicAdd(&denom[s], a);
    }
  }
}

__global__ __launch_bounds__(256) void k_agg(const uint4* __restrict__ hh4,
                                             const int* __restrict__ row_start,
                                             const int2* __restrict__ bucket,
                                             const float* __restrict__ denom,
                                             float* __restrict__ out, int n_nodes) {
  int lane = threadIdx.x & 63;
  int sub = lane >> 4, l16 = lane & 15;
  int d = blockIdx.x * 4 + (threadIdx.x >> 6);
  if (d >= n_nodes) return;
  int beg = row_start[d], end = row_start[d + 1];
  int cnt = end - beg;
  float a0 = 0.f, a1 = 0.f, a2 = 0.f, a3 = 0.f;
  float a4 = 0.f, a5 = 0.f, a6 = 0.f, a7 = 0.f;
  for (int base = 0; base < cnt; base += 64) {
    int nb = cnt - base; if (nb > 64) nb = 64;
    int2 ew = make_int2(0, 0);
    if (lane < nb) {
      ew = bucket[beg + base + lane];
      float w = __int_as_float(ew.y) / denom[ew.x];   // fold k_w here
      ew.y = __float_as_int(w);
    }
    int steps = (nb + 3) >> 2;
    for (int j = 0; j < steps; ++j) {
      int idx = j * 4 + sub;
      int s = __shfl(ew.x, idx);
      float w = __int_as_float(__shfl(ew.y, idx));
      if (idx < nb) {
        uint4 v = hh4[(size_t)s * 16 + l16];
        float2 f0 = unpack_f16(v.x), f1 = unpack_f16(v.y);
        float2 f2 = unpack_f16(v.z), f3 = unpack_f16(v.w);
        a0 = fmaf(w, f0.x, a0); a1 = fmaf(w, f0.y, a1);
        a2 = fmaf(w, f1.x, a2); a3 = fmaf(w, f1.y, a3);
        a4 = fmaf(w, f2.x, a4); a5 = fmaf(w, f2.y, a5);
        a6 = fmaf(w, f3.x, a6); a7 = fmaf(w, f3.y, a7);
      }
    }
  }
  #pragma unroll
  for (int off = 16; off < 64; off <<= 1) {
    a0 += __shfl_xor(a0, off); a1 += __shfl_xor(a1, off);
    a2 += __shfl_xor(a2, off); a3 += __shfl_xor(a3, off);
    a4 += __shfl_xor(a4, off); a5 += __shfl_xor(a5, off);
    a6 += __shfl_xor(a6, off); a7 += __shfl_xor(a7, off);
  }
  if (sub == 0) {
    *(float4*)&out[(size_t)d * 128 + l16 * 8]     = make_float4(a0, a1, a2, a3);
    *(float4*)&out[(size_t)d * 128 + l16 * 8 + 4] = make_float4(a4, a5, a6, a7);
  }
}

extern "C" void kernel_launch(void* const* d_in, const int* in_sizes, int n_in,
                              void* d_out, int out_size, void* d_ws, size_t ws_size,
                              hipStream_t stream) {
  const float* h   = (const float*)d_in[0];
  const int*   src = (const int*)d_in[1];
  const int*   dst = (const int*)d_in[2];
  const float* W1  = (const float*)d_in[3];
  const float* b1  = (const float*)d_in[4];
  const float* W2  = (const float*)d_in[5];
  const float* b2  = (const float*)d_in[6];
  float* out = (float*)d_out;

  int n_nodes = in_sizes[0] / 128;
  int n_edges = in_sizes[1];

  char* ws = (char*)d_ws;
  uint*   gh        = (uint*)ws;                            // n*64
  uint*   hh        = gh + (size_t)n_nodes * 64;            // n*64
  float*  denom     = (float*)(hh + (size_t)n_nodes * 64);  // n
  int*    counts    = (int*)(denom + n_nodes);              // n (cursor later)
  int*    row_start = counts + n_nodes;                     // n+1
  int*    partials  = row_start + n_nodes + 1;              // 256
  ushort* w1t       = (ushort*)(partials + 256);            // 16384 (32 KiB)
  int*    bsrc      = (int*)(w1t + 16384);                  // E
  int2*   bucket    = (int2*)(((uintptr_t)(bsrc + n_edges) + 15) & ~(uintptr_t)15);

  hipMemsetAsync(denom, 0, (size_t)2 * n_nodes * sizeof(float), stream);

  int chunk = (n_nodes + 255) / 256;
  int n_tiles = (n_nodes + 15) / 16;
  int nblk4 = (n_nodes + 3) / 4;
  k_misc <<<64 + 1024, 256, 0, stream>>>(W1, w1t, dst, counts, n_edges);
  k_gemm <<<(n_tiles + 3) / 4, 256, 0, stream>>>(h, w1t, gh, (uint4*)hh, n_nodes);
  k_scanA<<<256, 256, 0, stream>>>(counts, partials, n_nodes, chunk);
  k_scanB<<<1, 256, 0, stream>>>(partials, row_start, n_nodes, n_edges);
  k_scanC<<<256, 256, 0, stream>>>(counts, partials, row_start, n_nodes, chunk);
  k_fill0<<<1024, 256, 0, stream>>>(src, dst, row_start, counts, bsrc, n_edges);
  k_att2 <<<nblk4, 256, 0, stream>>>((const uint4*)gh, bsrc, row_start, b1, W2, b2,
                                     bucket, denom, n_nodes);
  k_agg  <<<nblk4, 256, 0, stream>>>((const uint4*)hh, row_start, bucket, denom, out, n_nodes);
}

// Round 8
// 155.626 us; speedup vs baseline: 1.0686x; 1.0236x over previous
//
#include <hip/hip_runtime.h>

// Pipeline (fp16-packed gathers, fp32 math, MFMA node-GEMM, dst-sorted attention):
//   k_prep : blocks<64: W1 -> W1^T bf16 pre-swizzled; blocks>=64: zero denom+counts
//   k_gemm : blocks<gemm_blocks: g = h@W1 via mfma + hh fp16 copy; rest: hist counts[dst]++
//   scanA/B/C : exclusive scan counts -> row_start; zero counts (cursor)
//   k_fill0: bsrc[i] = src of i-th dst-sorted edge
//   k_att2 : wave per dst; d-row in regs; 1 gather/edge, 2 edges in flight per sub;
//            bucket[i]=(s,att); denom[s]+=att
//   k_agg  : wave per dst; loader lane divides att/denom[s]; 2 rows in flight per sub

typedef unsigned int uint;
typedef unsigned short ushort;
typedef __attribute__((ext_vector_type(8))) short short8;
typedef __attribute__((ext_vector_type(4))) float f32x4;
typedef __attribute__((ext_vector_type(2))) _Float16 h2;

static __device__ __forceinline__ uint pack_f16(float a, float b) {
  _Float16 ha = (_Float16)a, hb = (_Float16)b;
  unsigned short ua = __builtin_bit_cast(unsigned short, ha);
  unsigned short ub = __builtin_bit_cast(unsigned short, hb);
  return ((uint)ub << 16) | ua;
}
static __device__ __forceinline__ float2 unpack_f16(uint u) {
  _Float16 lo = __builtin_bit_cast(_Float16, (unsigned short)(u & 0xffffu));
  _Float16 hi = __builtin_bit_cast(_Float16, (unsigned short)(u >> 16));
  return make_float2((float)lo, (float)hi);
}
static __device__ __forceinline__ h2 as_h2(uint u) { return __builtin_bit_cast(h2, u); }
static __device__ __forceinline__ h2 relu2(h2 a) {
  h2 r;
  r.x = a.x > (_Float16)0 ? a.x : (_Float16)0;
  r.y = a.y > (_Float16)0 ? a.y : (_Float16)0;
  return r;
}
static __device__ __forceinline__ float dot2acc(h2 a, h2 b, float c) {
#if __has_builtin(__builtin_amdgcn_fdot2)
  return __builtin_amdgcn_fdot2(a, b, c, false);
#else
  return c + (float)a.x * (float)b.x + (float)a.y * (float)b.y;
#endif
}
static __device__ __forceinline__ ushort f2bf(float x) {
  uint u = __float_as_uint(x);
  u += 0x7fffu + ((u >> 16) & 1u);   // RNE
  return (ushort)(u >> 16);
}

// blocks 0..63: W1[k][n] fp32 -> W1^T bf16 swizzled; blocks 64+: zero denom+counts
__global__ __launch_bounds__(256) void k_prep(const float* __restrict__ W1,
                                              ushort* __restrict__ w1t_swz,
                                              int* __restrict__ zbase, int zwords) {
  int b = blockIdx.x;
  if (b < 64) {
    int idx = b * 256 + threadIdx.x;
    int n = idx >> 7, k = idx & 127;
    float v = W1[k * 128 + n];
    int byte_off = n * 256 + ((k * 2) ^ ((n & 7) << 4));
    w1t_swz[byte_off >> 1] = f2bf(v);
  } else {
    int i = (b - 64) * 256 + threadIdx.x;
    int stride = (gridDim.x - 64) * 256;
    for (; i < zwords; i += stride) zbase[i] = 0;
  }
}

__global__ __launch_bounds__(256) void k_gemm(const float* __restrict__ h,
                                              const ushort* __restrict__ w1t_swz,
                                              uint* __restrict__ gh,
                                              uint4* __restrict__ hh4,
                                              int n_nodes,
                                              const int* __restrict__ dst,
                                              int* __restrict__ counts,
                                              int n_edges, int gemm_blocks) {
  if ((int)blockIdx.x >= gemm_blocks) {          // histogram tail blocks
    int hb = blockIdx.x - gemm_blocks;
    int i = hb * 256 + threadIdx.x;
    int stride = (gridDim.x - gemm_blocks) * 256;
    for (int e = i; e < n_edges; e += stride) atomicAdd(&counts[dst[e]], 1);
    return;
  }
  __shared__ ushort w1s[16384];   // 32 KiB swizzled W1^T image
  int tid = threadIdx.x;
  {
    const uint4* srcw = (const uint4*)w1t_swz;
    uint4* dstw = (uint4*)w1s;
    #pragma unroll
    for (int i = 0; i < 8; ++i) dstw[tid + 256 * i] = srcw[tid + 256 * i];
  }
  __syncthreads();
  int wave = tid >> 6, lane = tid & 63;
  int tile = blockIdx.x * 4 + wave;
  if (tile * 16 >= n_nodes) return;
  int n0 = tile * 16;
  int l15 = lane & 15, kq = lane >> 4;
  int row = n0 + l15;

  f32x4 acc[8];
  #pragma unroll
  for (int ct = 0; ct < 8; ++ct) acc[ct] = (f32x4){0.f, 0.f, 0.f, 0.f};

  #pragma unroll
  for (int kb = 0; kb < 4; ++kb) {
    const float* hp = &h[(size_t)row * 128 + kb * 32 + kq * 8];
    float4 p0 = *(const float4*)hp;
    float4 p1 = *(const float4*)(hp + 4);
    short8 a;
    a[0] = (short)f2bf(p0.x); a[1] = (short)f2bf(p0.y);
    a[2] = (short)f2bf(p0.z); a[3] = (short)f2bf(p0.w);
    a[4] = (short)f2bf(p1.x); a[5] = (short)f2bf(p1.y);
    a[6] = (short)f2bf(p1.z); a[7] = (short)f2bf(p1.w);
    uint4 hv;
    hv.x = pack_f16(p0.x, p0.y); hv.y = pack_f16(p0.z, p0.w);
    hv.z = pack_f16(p1.x, p1.y); hv.w = pack_f16(p1.z, p1.w);
    hh4[(size_t)row * 16 + kb * 4 + kq] = hv;
    #pragma unroll
    for (int ct = 0; ct < 8; ++ct) {
      int n = ct * 16 + l15;
      int byte_off = n * 256 + (((kb * 64) + kq * 16) ^ ((n & 7) << 4));
      short8 b = *(const short8*)((const char*)w1s + byte_off);
      acc[ct] = __builtin_amdgcn_mfma_f32_16x16x32_bf16(a, b, acc[ct], 0, 0, 0);
    }
  }
  ushort* gh16 = (ushort*)gh;
  #pragma unroll
  for (int ct = 0; ct < 8; ++ct) {
    #pragma unroll
    for (int r = 0; r < 4; ++r) {
      int orow = n0 + kq * 4 + r;
      _Float16 v = (_Float16)acc[ct][r];
      gh16[(size_t)orow * 128 + ct * 16 + l15] = __builtin_bit_cast(unsigned short, v);
    }
  }
}

__global__ __launch_bounds__(256) void k_scanA(const int* __restrict__ counts,
                                               int* __restrict__ partials,
                                               int n, int chunk) {
  __shared__ int red[256];
  int b = blockIdx.x, t = threadIdx.x;
  int idx = b * chunk + t;
  red[t] = (t < chunk && idx < n) ? counts[idx] : 0;
  __syncthreads();
  for (int off = 128; off > 0; off >>= 1) {
    if (t < off) red[t] += red[t + off];
    __syncthreads();
  }
  if (t == 0) partials[b] = red[0];
}

__global__ __launch_bounds__(256) void k_scanB(int* __restrict__ partials,
                                               int* __restrict__ row_start,
                                               int n, int total) {
  __shared__ int p[256];
  int t = threadIdx.x;
  int orig = partials[t];
  p[t] = orig;
  __syncthreads();
  #pragma unroll
  for (int off = 1; off < 256; off <<= 1) {
    int v = (t >= off) ? p[t - off] : 0;
    __syncthreads();
    p[t] += v;
    __syncthreads();
  }
  partials[t] = p[t] - orig;
  if (t == 0) row_start[n] = total;
}

__global__ __launch_bounds__(256) void k_scanC(int* __restrict__ counts,
                                               const int* __restrict__ partials,
                                               int* __restrict__ row_start,
                                               int n, int chunk) {
  __shared__ int p[256];
  int b = blockIdx.x, t = threadIdx.x;
  int idx = b * chunk + t;
  bool ok = (t < chunk && idx < n);
  int orig = ok ? counts[idx] : 0;
  p[t] = orig;
  __syncthreads();
  #pragma unroll
  for (int off = 1; off < 256; off <<= 1) {
    int v = (t >= off) ? p[t - off] : 0;
    __syncthreads();
    p[t] += v;
    __syncthreads();
  }
  if (ok) {
    row_start[idx] = partials[b] + p[t] - orig;
    counts[idx] = 0;  // becomes cursor for k_fill0
  }
}

__global__ __launch_bounds__(256) void k_fill0(const int* __restrict__ src,
                                               const int* __restrict__ dst,
                                               const int* __restrict__ row_start,
                                               int* __restrict__ cursor,
                                               int* __restrict__ bsrc,
                                               int n_edges) {
  int i = blockIdx.x * blockDim.x + threadIdx.x;
  int stride = gridDim.x * blockDim.x;
  for (int e = i; e < n_edges; e += stride) {
    int d = dst[e];
    int pos = atomicAdd(&cursor[d], 1);
    bsrc[row_start[d] + pos] = src[e];
  }
}

// wave per dst: d-row in regs; 2 edges in flight per 16-lane sub-group
__global__ __launch_bounds__(256) void k_att2(const uint4* __restrict__ gh4,
                                              const int* __restrict__ bsrc,
                                              const int* __restrict__ row_start,
                                              const float* __restrict__ b1,
                                              const float* __restrict__ W2,
                                              const float* __restrict__ b2,
                                              int2* __restrict__ bucket,
                                              float* __restrict__ denom,
                                              int n_nodes) {
  int lane = threadIdx.x & 63;
  int sub = lane >> 4, l16 = lane & 15;
  int d = blockIdx.x * 4 + (threadIdx.x >> 6);
  if (d >= n_nodes) return;
  int beg = row_start[d], end = row_start[d + 1];
  if (beg == end) return;
  float4 b1a = *(const float4*)&b1[l16 * 8];
  float4 b1b = *(const float4*)&b1[l16 * 8 + 4];
  float4 w2a = *(const float4*)&W2[l16 * 8];
  float4 w2b = *(const float4*)&W2[l16 * 8 + 4];
  float b2v = b2[0];
  uint4 ud = gh4[(size_t)d * 16 + l16];
  float2 d0 = unpack_f16(ud.x), d1 = unpack_f16(ud.y);
  float2 d2 = unpack_f16(ud.z), d3 = unpack_f16(ud.w);
  h2 c0, c1, c2, c3, wh0, wh1, wh2, wh3;
  c0.x = (_Float16)(b1a.x - d0.x); c0.y = (_Float16)(b1a.y - d0.y);
  c1.x = (_Float16)(b1a.z - d1.x); c1.y = (_Float16)(b1a.w - d1.y);
  c2.x = (_Float16)(b1b.x - d2.x); c2.y = (_Float16)(b1b.y - d2.y);
  c3.x = (_Float16)(b1b.z - d3.x); c3.y = (_Float16)(b1b.w - d3.y);
  wh0.x = (_Float16)w2a.x; wh0.y = (_Float16)w2a.y;
  wh1.x = (_Float16)w2a.z; wh1.y = (_Float16)w2a.w;
  wh2.x = (_Float16)w2b.x; wh2.y = (_Float16)w2b.y;
  wh3.x = (_Float16)w2b.z; wh3.y = (_Float16)w2b.w;
  for (int jb = beg; jb < end; jb += 8) {
    int j0 = jb + sub, j1 = jb + sub + 4;
    bool v0 = j0 < end, v1 = j1 < end;
    int s0 = 0, s1 = 0;
    float acc0 = 0.f, acc1 = 0.f;
    if (v0) s0 = bsrc[j0];
    if (v1) s1 = bsrc[j1];
    uint4 ua, ub;
    if (v0) ua = gh4[(size_t)s0 * 16 + l16];
    if (v1) ub = gh4[(size_t)s1 * 16 + l16];
    if (v0) {
      acc0 = dot2acc(relu2(as_h2(ua.x) + c0), wh0, acc0);
      acc0 = dot2acc(relu2(as_h2(ua.y) + c1), wh1, acc0);
      acc0 = dot2acc(relu2(as_h2(ua.z) + c2), wh2, acc0);
      acc0 = dot2acc(relu2(as_h2(ua.w) + c3), wh3, acc0);
    }
    if (v1) {
      acc1 = dot2acc(relu2(as_h2(ub.x) + c0), wh0, acc1);
      acc1 = dot2acc(relu2(as_h2(ub.y) + c1), wh1, acc1);
      acc1 = dot2acc(relu2(as_h2(ub.z) + c2), wh2, acc1);
      acc1 = dot2acc(relu2(as_h2(ub.w) + c3), wh3, acc1);
    }
    acc0 += __shfl_xor(acc0, 1); acc1 += __shfl_xor(acc1, 1);
    acc0 += __shfl_xor(acc0, 2); acc1 += __shfl_xor(acc1, 2);
    acc0 += __shfl_xor(acc0, 4); acc1 += __shfl_xor(acc1, 4);
    acc0 += __shfl_xor(acc0, 8); acc1 += __shfl_xor(acc1, 8);
    if (l16 == 0) {
      if (v0) {
        float a = fmaxf(acc0 + b2v, 0.f);
        a = 1.f / (1.f + __expf(-a));
        bucket[j0] = make_int2(s0, __float_as_int(a));
        atomicAdd(&denom[s0], a);
      }
      if (v1) {
        float a = fmaxf(acc1 + b2v, 0.f);
        a = 1.f / (1.f + __expf(-a));
        bucket[j1] = make_int2(s1, __float_as_int(a));
        atomicAdd(&denom[s1], a);
      }
    }
  }
}

__global__ __launch_bounds__(256) void k_agg(const uint4* __restrict__ hh4,
                                             const int* __restrict__ row_start,
                                             const int2* __restrict__ bucket,
                                             const float* __restrict__ denom,
                                             float* __restrict__ out, int n_nodes) {
  int lane = threadIdx.x & 63;
  int sub = lane >> 4, l16 = lane & 15;
  int d = blockIdx.x * 4 + (threadIdx.x >> 6);
  if (d >= n_nodes) return;
  int beg = row_start[d], end = row_start[d + 1];
  int cnt = end - beg;
  float a0 = 0.f, a1 = 0.f, a2 = 0.f, a3 = 0.f;
  float a4 = 0.f, a5 = 0.f, a6 = 0.f, a7 = 0.f;
  for (int base = 0; base < cnt; base += 64) {
    int nb = cnt - base; if (nb > 64) nb = 64;
    int2 ew = make_int2(0, 0);
    if (lane < nb) {
      ew = bucket[beg + base + lane];
      float w = __int_as_float(ew.y) / denom[ew.x];   // normalize here
      ew.y = __float_as_int(w);
    }
    int steps = (nb + 3) >> 2;
    int jj = 0;
    for (; jj + 2 <= steps; jj += 2) {
      int i0 = jj * 4 + sub, i1 = i0 + 4;
      int sA = __shfl(ew.x, i0), sB = __shfl(ew.x, i1);
      float wA = __int_as_float(__shfl(ew.y, i0));
      float wB = __int_as_float(__shfl(ew.y, i1));
      bool vA = i0 < nb, vB = i1 < nb;
      uint4 va, vb;
      if (vA) va = hh4[(size_t)sA * 16 + l16];
      if (vB) vb = hh4[(size_t)sB * 16 + l16];
      if (vA) {
        float2 f0 = unpack_f16(va.x), f1 = unpack_f16(va.y);
        float2 f2 = unpack_f16(va.z), f3 = unpack_f16(va.w);
        a0 = fmaf(wA, f0.x, a0); a1 = fmaf(wA, f0.y, a1);
        a2 = fmaf(wA, f1.x, a2); a3 = fmaf(wA, f1.y, a3);
        a4 = fmaf(wA, f2.x, a4); a5 = fmaf(wA, f2.y, a5);
        a6 = fmaf(wA, f3.x, a6); a7 = fmaf(wA, f3.y, a7);
      }
      if (vB) {
        float2 f0 = unpack_f16(vb.x), f1 = unpack_f16(vb.y);
        float2 f2 = unpack_f16(vb.z), f3 = unpack_f16(vb.w);
        a0 = fmaf(wB, f0.x, a0); a1 = fmaf(wB, f0.y, a1);
        a2 = fmaf(wB, f1.x, a2); a3 = fmaf(wB, f1.y, a3);
        a4 = fmaf(wB, f2.x, a4); a5 = fmaf(wB, f2.y, a5);
        a6 = fmaf(wB, f3.x, a6); a7 = fmaf(wB, f3.y, a7);
      }
    }
    if (jj < steps) {
      int i0 = jj * 4 + sub;
      int sA = __shfl(ew.x, i0);
      float wA = __int_as_float(__shfl(ew.y, i0));
      if (i0 < nb) {
        uint4 va = hh4[(size_t)sA * 16 + l16];
        float2 f0 = unpack_f16(va.x), f1 = unpack_f16(va.y);
        float2 f2 = unpack_f16(va.z), f3 = unpack_f16(va.w);
        a0 = fmaf(wA, f0.x, a0); a1 = fmaf(wA, f0.y, a1);
        a2 = fmaf(wA, f1.x, a2); a3 = fmaf(wA, f1.y, a3);
        a4 = fmaf(wA, f2.x, a4); a5 = fmaf(wA, f2.y, a5);
        a6 = fmaf(wA, f3.x, a6); a7 = fmaf(wA, f3.y, a7);
      }
    }
  }
  #pragma unroll
  for (int off = 16; off < 64; off <<= 1) {
    a0 += __shfl_xor(a0, off); a1 += __shfl_xor(a1, off);
    a2 += __shfl_xor(a2, off); a3 += __shfl_xor(a3, off);
    a4 += __shfl_xor(a4, off); a5 += __shfl_xor(a5, off);
    a6 += __shfl_xor(a6, off); a7 += __shfl_xor(a7, off);
  }
  if (sub == 0) {
    *(float4*)&out[(size_t)d * 128 + l16 * 8]     = make_float4(a0, a1, a2, a3);
    *(float4*)&out[(size_t)d * 128 + l16 * 8 + 4] = make_float4(a4, a5, a6, a7);
  }
}

extern "C" void kernel_launch(void* const* d_in, const int* in_sizes, int n_in,
                              void* d_out, int out_size, void* d_ws, size_t ws_size,
                              hipStream_t stream) {
  const float* h   = (const float*)d_in[0];
  const int*   src = (const int*)d_in[1];
  const int*   dst = (const int*)d_in[2];
  const float* W1  = (const float*)d_in[3];
  const float* b1  = (const float*)d_in[4];
  const float* W2  = (const float*)d_in[5];
  const float* b2  = (const float*)d_in[6];
  float* out = (float*)d_out;

  int n_nodes = in_sizes[0] / 128;
  int n_edges = in_sizes[1];

  char* ws = (char*)d_ws;
  uint*   gh        = (uint*)ws;                            // n*64
  uint*   hh        = gh + (size_t)n_nodes * 64;            // n*64
  float*  denom     = (float*)(hh + (size_t)n_nodes * 64);  // n
  int*    counts    = (int*)(denom + n_nodes);              // n (cursor later)
  int*    row_start = counts + n_nodes;                     // n+1
  int*    partials  = row_start + n_nodes + 1;              // 256
  ushort* w1t       = (ushort*)(partials + 256);            // 16384 (32 KiB)
  int*    bsrc      = (int*)(w1t + 16384);                  // E
  int2*   bucket    = (int2*)(((uintptr_t)(bsrc + n_edges) + 15) & ~(uintptr_t)15);

  int chunk = (n_nodes + 255) / 256;
  int n_tiles = (n_nodes + 15) / 16;
  int gemm_blocks = (n_tiles + 3) / 4;
  int nblk4 = (n_nodes + 3) / 4;
  // k_prep: 64 transpose blocks + 16 zero blocks (denom+counts = 2n words)
  k_prep <<<64 + 16, 256, 0, stream>>>(W1, w1t, (int*)denom, 2 * n_nodes);
  k_gemm <<<gemm_blocks + 256, 256, 0, stream>>>(h, w1t, gh, (uint4*)hh, n_nodes,
                                                 dst, counts, n_edges, gemm_blocks);
  k_scanA<<<256, 256, 0, stream>>>(counts, partials, n_nodes, chunk);
  k_scanB<<<1, 256, 0, stream>>>(partials, row_start, n_nodes, n_edges);
  k_scanC<<<256, 256, 0, stream>>>(counts, partials, row_start, n_nodes, chunk);
  k_fill0<<<1024, 256, 0, stream>>>(src, dst, row_start, counts, bsrc, n_edges);
  k_att2 <<<nblk4, 256, 0, stream>>>((const uint4*)gh, bsrc, row_start, b1, W2, b2,
                                     bucket, denom, n_nodes);
  k_agg  <<<nblk4, 256, 0, stream>>>((const uint4*)hh, row_start, bucket, denom, out, n_nodes);
}

// Round 9
// 135.846 us; speedup vs baseline: 1.2242x; 1.1456x over previous
//
#include <hip/hip_runtime.h>

// Pipeline (fp16-packed gathers, fp32 accum, MFMA node-GEMM, dst-sorted attention):
//   k_prep : blocks<64: W1 -> W1^T bf16 pre-swizzled; blocks>=64: zero denom+counts
//   k_gemm : blocks<gemm_blocks: g=h@W1 (mfma) + hh fp16 copy; tail: hist + rank[e]
//   k_scanA: 256-block chunk reduce -> partials
//   k_scanC2: merged scanB+scanC (each block re-scans partials) -> row_start
//   k_fill0: bsrc[row_start[dst[e]] + rank[e]] = src[e]   (no atomics)
//   k_att2 : one dst per 16-lane sub (4 dst/wave); d-row in regs; 2 edges in flight;
//            bucket[j]=(s,att); denom[s]+=att
//   k_agg  : one dst per sub; broadcast bucket/denom loads; no shuffles; out stores

typedef unsigned int uint;
typedef unsigned short ushort;
typedef __attribute__((ext_vector_type(8))) short short8;
typedef __attribute__((ext_vector_type(4))) float f32x4;
typedef __attribute__((ext_vector_type(2))) _Float16 h2;

static __device__ __forceinline__ uint pack_f16(float a, float b) {
  _Float16 ha = (_Float16)a, hb = (_Float16)b;
  unsigned short ua = __builtin_bit_cast(unsigned short, ha);
  unsigned short ub = __builtin_bit_cast(unsigned short, hb);
  return ((uint)ub << 16) | ua;
}
static __device__ __forceinline__ float2 unpack_f16(uint u) {
  _Float16 lo = __builtin_bit_cast(_Float16, (unsigned short)(u & 0xffffu));
  _Float16 hi = __builtin_bit_cast(_Float16, (unsigned short)(u >> 16));
  return make_float2((float)lo, (float)hi);
}
static __device__ __forceinline__ h2 as_h2(uint u) { return __builtin_bit_cast(h2, u); }
static __device__ __forceinline__ h2 relu2(h2 a) {
  h2 r;
  r.x = a.x > (_Float16)0 ? a.x : (_Float16)0;
  r.y = a.y > (_Float16)0 ? a.y : (_Float16)0;
  return r;
}
static __device__ __forceinline__ float dot2acc(h2 a, h2 b, float c) {
#if __has_builtin(__builtin_amdgcn_fdot2)
  return __builtin_amdgcn_fdot2(a, b, c, false);
#else
  return c + (float)a.x * (float)b.x + (float)a.y * (float)b.y;
#endif
}
static __device__ __forceinline__ ushort f2bf(float x) {
  uint u = __float_as_uint(x);
  u += 0x7fffu + ((u >> 16) & 1u);   // RNE
  return (ushort)(u >> 16);
}

// blocks 0..63: W1[k][n] fp32 -> W1^T bf16 swizzled; blocks 64+: zero denom+counts
__global__ __launch_bounds__(256) void k_prep(const float* __restrict__ W1,
                                              ushort* __restrict__ w1t_swz,
                                              int* __restrict__ zbase, int zwords) {
  int b = blockIdx.x;
  if (b < 64) {
    int idx = b * 256 + threadIdx.x;
    int n = idx >> 7, k = idx & 127;
    float v = W1[k * 128 + n];
    int byte_off = n * 256 + ((k * 2) ^ ((n & 7) << 4));
    w1t_swz[byte_off >> 1] = f2bf(v);
  } else {
    int i = (b - 64) * 256 + threadIdx.x;
    int stride = (gridDim.x - 64) * 256;
    for (; i < zwords; i += stride) zbase[i] = 0;
  }
}

__global__ __launch_bounds__(256) void k_gemm(const float* __restrict__ h,
                                              const ushort* __restrict__ w1t_swz,
                                              uint* __restrict__ gh,
                                              uint4* __restrict__ hh4,
                                              int n_nodes,
                                              const int* __restrict__ dst,
                                              int* __restrict__ counts,
                                              int* __restrict__ rank,
                                              int n_edges, int gemm_blocks) {
  if ((int)blockIdx.x >= gemm_blocks) {          // histogram + rank tail blocks
    int hb = blockIdx.x - gemm_blocks;
    int i = hb * 256 + threadIdx.x;
    int stride = (gridDim.x - gemm_blocks) * 256;
    for (int e = i; e < n_edges; e += stride) {
      int r = atomicAdd(&counts[dst[e]], 1);
      rank[e] = r;
    }
    return;
  }
  __shared__ ushort w1s[16384];   // 32 KiB swizzled W1^T image
  int tid = threadIdx.x;
  {
    const uint4* srcw = (const uint4*)w1t_swz;
    uint4* dstw = (uint4*)w1s;
    #pragma unroll
    for (int i = 0; i < 8; ++i) dstw[tid + 256 * i] = srcw[tid + 256 * i];
  }
  __syncthreads();
  int wave = tid >> 6, lane = tid & 63;
  int tile = blockIdx.x * 4 + wave;
  if (tile * 16 >= n_nodes) return;
  int n0 = tile * 16;
  int l15 = lane & 15, kq = lane >> 4;
  int row = n0 + l15;

  f32x4 acc[8];
  #pragma unroll
  for (int ct = 0; ct < 8; ++ct) acc[ct] = (f32x4){0.f, 0.f, 0.f, 0.f};

  #pragma unroll
  for (int kb = 0; kb < 4; ++kb) {
    const float* hp = &h[(size_t)row * 128 + kb * 32 + kq * 8];
    float4 p0 = *(const float4*)hp;
    float4 p1 = *(const float4*)(hp + 4);
    short8 a;
    a[0] = (short)f2bf(p0.x); a[1] = (short)f2bf(p0.y);
    a[2] = (short)f2bf(p0.z); a[3] = (short)f2bf(p0.w);
    a[4] = (short)f2bf(p1.x); a[5] = (short)f2bf(p1.y);
    a[6] = (short)f2bf(p1.z); a[7] = (short)f2bf(p1.w);
    uint4 hv;
    hv.x = pack_f16(p0.x, p0.y); hv.y = pack_f16(p0.z, p0.w);
    hv.z = pack_f16(p1.x, p1.y); hv.w = pack_f16(p1.z, p1.w);
    hh4[(size_t)row * 16 + kb * 4 + kq] = hv;
    #pragma unroll
    for (int ct = 0; ct < 8; ++ct) {
      int n = ct * 16 + l15;
      int byte_off = n * 256 + (((kb * 64) + kq * 16) ^ ((n & 7) << 4));
      short8 b = *(const short8*)((const char*)w1s + byte_off);
      acc[ct] = __builtin_amdgcn_mfma_f32_16x16x32_bf16(a, b, acc[ct], 0, 0, 0);
    }
  }
  ushort* gh16 = (ushort*)gh;
  #pragma unroll
  for (int ct = 0; ct < 8; ++ct) {
    #pragma unroll
    for (int r = 0; r < 4; ++r) {
      int orow = n0 + kq * 4 + r;
      _Float16 v = (_Float16)acc[ct][r];
      gh16[(size_t)orow * 128 + ct * 16 + l15] = __builtin_bit_cast(unsigned short, v);
    }
  }
}

__global__ __launch_bounds__(256) void k_scanA(const int* __restrict__ counts,
                                               int* __restrict__ partials,
                                               int n, int chunk) {
  __shared__ int red[256];
  int b = blockIdx.x, t = threadIdx.x;
  int idx = b * chunk + t;
  red[t] = (t < chunk && idx < n) ? counts[idx] : 0;
  __syncthreads();
  for (int off = 128; off > 0; off >>= 1) {
    if (t < off) red[t] += red[t + off];
    __syncthreads();
  }
  if (t == 0) partials[b] = red[0];
}

// merged scanB+scanC: each block re-scans the 256 partials to get its base
__global__ __launch_bounds__(256) void k_scanC2(const int* __restrict__ counts,
                                                const int* __restrict__ partials,
                                                int* __restrict__ row_start,
                                                int n, int chunk, int total) {
  __shared__ int bp[256];
  __shared__ int p[256];
  int b = blockIdx.x, t = threadIdx.x;
  bp[t] = partials[t];
  __syncthreads();
  #pragma unroll
  for (int off = 1; off < 256; off <<= 1) {
    int v = (t >= off) ? bp[t - off] : 0;
    __syncthreads();
    bp[t] += v;
    __syncthreads();
  }
  int base = (b == 0) ? 0 : bp[b - 1];
  int idx = b * chunk + t;
  bool ok = (t < chunk && idx < n);
  int orig = ok ? counts[idx] : 0;
  p[t] = orig;
  __syncthreads();
  #pragma unroll
  for (int off = 1; off < 256; off <<= 1) {
    int v = (t >= off) ? p[t - off] : 0;
    __syncthreads();
    p[t] += v;
    __syncthreads();
  }
  if (ok) row_start[idx] = base + p[t] - orig;
  if (b == 0 && t == 0) row_start[n] = total;
}

__global__ __launch_bounds__(256) void k_fill0(const int* __restrict__ src,
                                               const int* __restrict__ dst,
                                               const int* __restrict__ row_start,
                                               const int* __restrict__ rank,
                                               int* __restrict__ bsrc,
                                               int n_edges) {
  int i = blockIdx.x * blockDim.x + threadIdx.x;
  int stride = gridDim.x * blockDim.x;
  for (int e = i; e < n_edges; e += stride) {
    bsrc[row_start[dst[e]] + rank[e]] = src[e];
  }
}

// one dst per 16-lane sub (4 dst/wave); d-row in regs; 2 edges in flight per sub
__global__ __launch_bounds__(256) void k_att2(const uint4* __restrict__ gh4,
                                              const int* __restrict__ bsrc,
                                              const int* __restrict__ row_start,
                                              const float* __restrict__ b1,
                                              const float* __restrict__ W2,
                                              const float* __restrict__ b2,
                                              int2* __restrict__ bucket,
                                              float* __restrict__ denom,
                                              int n_nodes) {
  int lane = threadIdx.x & 63;
  int sub = lane >> 4, l16 = lane & 15;
  int wavei = threadIdx.x >> 6;
  int d = blockIdx.x * 16 + wavei * 4 + sub;
  int beg = 0, end = 0;
  if (d < n_nodes) { beg = row_start[d]; end = row_start[d + 1]; }
  float4 b1a = *(const float4*)&b1[l16 * 8];
  float4 b1b = *(const float4*)&b1[l16 * 8 + 4];
  float4 w2a = *(const float4*)&W2[l16 * 8];
  float4 w2b = *(const float4*)&W2[l16 * 8 + 4];
  float b2v = b2[0];
  h2 c0, c1, c2, c3, wh0, wh1, wh2, wh3;
  wh0.x = (_Float16)w2a.x; wh0.y = (_Float16)w2a.y;
  wh1.x = (_Float16)w2a.z; wh1.y = (_Float16)w2a.w;
  wh2.x = (_Float16)w2b.x; wh2.y = (_Float16)w2b.y;
  wh3.x = (_Float16)w2b.z; wh3.y = (_Float16)w2b.w;
  c0 = (h2)(_Float16)0; c1 = c0; c2 = c0; c3 = c0;
  if (beg < end) {
    uint4 ud = gh4[(size_t)d * 16 + l16];
    float2 d0 = unpack_f16(ud.x), d1 = unpack_f16(ud.y);
    float2 d2 = unpack_f16(ud.z), d3 = unpack_f16(ud.w);
    c0.x = (_Float16)(b1a.x - d0.x); c0.y = (_Float16)(b1a.y - d0.y);
    c1.x = (_Float16)(b1a.z - d1.x); c1.y = (_Float16)(b1a.w - d1.y);
    c2.x = (_Float16)(b1b.x - d2.x); c2.y = (_Float16)(b1b.y - d2.y);
    c3.x = (_Float16)(b1b.z - d3.x); c3.y = (_Float16)(b1b.w - d3.y);
  }
  for (int j0 = beg; j0 < end; j0 += 2) {
    int j1 = j0 + 1;
    bool v1 = j1 < end;
    int s0 = bsrc[j0];
    int s1 = v1 ? bsrc[j1] : 0;
    uint4 ua = gh4[(size_t)s0 * 16 + l16];
    uint4 ub;
    if (v1) ub = gh4[(size_t)s1 * 16 + l16];
    float acc0 = 0.f, acc1 = 0.f;
    acc0 = dot2acc(relu2(as_h2(ua.x) + c0), wh0, acc0);
    acc0 = dot2acc(relu2(as_h2(ua.y) + c1), wh1, acc0);
    acc0 = dot2acc(relu2(as_h2(ua.z) + c2), wh2, acc0);
    acc0 = dot2acc(relu2(as_h2(ua.w) + c3), wh3, acc0);
    if (v1) {
      acc1 = dot2acc(relu2(as_h2(ub.x) + c0), wh0, acc1);
      acc1 = dot2acc(relu2(as_h2(ub.y) + c1), wh1, acc1);
      acc1 = dot2acc(relu2(as_h2(ub.z) + c2), wh2, acc1);
      acc1 = dot2acc(relu2(as_h2(ub.w) + c3), wh3, acc1);
    }
    // reduce within the 16-lane sub only
    acc0 += __shfl_xor(acc0, 1); acc1 += __shfl_xor(acc1, 1);
    acc0 += __shfl_xor(acc0, 2); acc1 += __shfl_xor(acc1, 2);
    acc0 += __shfl_xor(acc0, 4); acc1 += __shfl_xor(acc1, 4);
    acc0 += __shfl_xor(acc0, 8); acc1 += __shfl_xor(acc1, 8);
    if (l16 == 0) {
      float a = fmaxf(acc0 + b2v, 0.f);
      a = 1.f / (1.f + __expf(-a));
      bucket[j0] = make_int2(s0, __float_as_int(a));
      atomicAdd(&denom[s0], a);
      if (v1) {
        float a1 = fmaxf(acc1 + b2v, 0.f);
        a1 = 1.f / (1.f + __expf(-a1));
        bucket[j1] = make_int2(s1, __float_as_int(a1));
        atomicAdd(&denom[s1], a1);
      }
    }
  }
}

// one dst per sub; broadcast bucket/denom loads; no shuffles
__global__ __launch_bounds__(256) void k_agg(const uint4* __restrict__ hh4,
                                             const int* __restrict__ row_start,
                                             const int2* __restrict__ bucket,
                                             const float* __restrict__ denom,
                                             float* __restrict__ out, int n_nodes) {
  int lane = threadIdx.x & 63;
  int sub = lane >> 4, l16 = lane & 15;
  int wavei = threadIdx.x >> 6;
  int d = blockIdx.x * 16 + wavei * 4 + sub;
  int beg = 0, end = 0;
  if (d < n_nodes) { beg = row_start[d]; end = row_start[d + 1]; }
  float a0 = 0.f, a1 = 0.f, a2 = 0.f, a3 = 0.f;
  float a4 = 0.f, a5 = 0.f, a6 = 0.f, a7 = 0.f;
  for (int j0 = beg; j0 < end; j0 += 2) {
    int j1 = j0 + 1;
    bool v1 = j1 < end;
    int2 e0 = bucket[j0];
    int2 e1 = v1 ? bucket[j1] : make_int2(0, 0);
    float w0 = __int_as_float(e0.y) / denom[e0.x];
    float w1 = v1 ? __int_as_float(e1.y) / denom[e1.x] : 0.f;
    uint4 va = hh4[(size_t)e0.x * 16 + l16];
    uint4 vb;
    if (v1) vb = hh4[(size_t)e1.x * 16 + l16];
    {
      float2 f0 = unpack_f16(va.x), f1 = unpack_f16(va.y);
      float2 f2 = unpack_f16(va.z), f3 = unpack_f16(va.w);
      a0 = fmaf(w0, f0.x, a0); a1 = fmaf(w0, f0.y, a1);
      a2 = fmaf(w0, f1.x, a2); a3 = fmaf(w0, f1.y, a3);
      a4 = fmaf(w0, f2.x, a4); a5 = fmaf(w0, f2.y, a5);
      a6 = fmaf(w0, f3.x, a6); a7 = fmaf(w0, f3.y, a7);
    }
    if (v1) {
      float2 f0 = unpack_f16(vb.x), f1 = unpack_f16(vb.y);
      float2 f2 = unpack_f16(vb.z), f3 = unpack_f16(vb.w);
      a0 = fmaf(w1, f0.x, a0); a1 = fmaf(w1, f0.y, a1);
      a2 = fmaf(w1, f1.x, a2); a3 = fmaf(w1, f1.y, a3);
      a4 = fmaf(w1, f2.x, a4); a5 = fmaf(w1, f2.y, a5);
      a6 = fmaf(w1, f3.x, a6); a7 = fmaf(w1, f3.y, a7);
    }
  }
  if (d < n_nodes) {
    *(float4*)&out[(size_t)d * 128 + l16 * 8]     = make_float4(a0, a1, a2, a3);
    *(float4*)&out[(size_t)d * 128 + l16 * 8 + 4] = make_float4(a4, a5, a6, a7);
  }
}

extern "C" void kernel_launch(void* const* d_in, const int* in_sizes, int n_in,
                              void* d_out, int out_size, void* d_ws, size_t ws_size,
                              hipStream_t stream) {
  const float* h   = (const float*)d_in[0];
  const int*   src = (const int*)d_in[1];
  const int*   dst = (const int*)d_in[2];
  const float* W1  = (const float*)d_in[3];
  const float* b1  = (const float*)d_in[4];
  const float* W2  = (const float*)d_in[5];
  const float* b2  = (const float*)d_in[6];
  float* out = (float*)d_out;

  int n_nodes = in_sizes[0] / 128;
  int n_edges = in_sizes[1];

  char* ws = (char*)d_ws;
  uint*   gh        = (uint*)ws;                            // n*64
  uint*   hh        = gh + (size_t)n_nodes * 64;            // n*64
  float*  denom     = (float*)(hh + (size_t)n_nodes * 64);  // n
  int*    counts    = (int*)(denom + n_nodes);              // n
  int*    row_start = counts + n_nodes;                     // n+1
  int*    partials  = row_start + n_nodes + 1;              // 256
  ushort* w1t       = (ushort*)(partials + 256);            // 16384 (32 KiB)
  int*    bsrc      = (int*)(w1t + 16384);                  // E
  int*    rank      = bsrc + n_edges;                       // E
  int2*   bucket    = (int2*)(((uintptr_t)(rank + n_edges) + 15) & ~(uintptr_t)15);

  int chunk = (n_nodes + 255) / 256;
  int n_tiles = (n_nodes + 15) / 16;
  int gemm_blocks = (n_tiles + 3) / 4;
  int nblk16 = (n_nodes + 15) / 16;
  k_prep  <<<64 + 16, 256, 0, stream>>>(W1, w1t, (int*)denom, 2 * n_nodes);
  k_gemm  <<<gemm_blocks + 256, 256, 0, stream>>>(h, w1t, gh, (uint4*)hh, n_nodes,
                                                  dst, counts, rank, n_edges, gemm_blocks);
  k_scanA <<<256, 256, 0, stream>>>(counts, partials, n_nodes, chunk);
  k_scanC2<<<256, 256, 0, stream>>>(counts, partials, row_start, n_nodes, chunk, n_edges);
  k_fill0 <<<1024, 256, 0, stream>>>(src, dst, row_start, rank, bsrc, n_edges);
  k_att2  <<<nblk16, 256, 0, stream>>>((const uint4*)gh, bsrc, row_start, b1, W2, b2,
                                       bucket, denom, n_nodes);
  k_agg   <<<nblk16, 256, 0, stream>>>((const uint4*)hh, row_start, bucket, denom, out, n_nodes);
}

// Round 10
// 135.023 us; speedup vs baseline: 1.2317x; 1.0061x over previous
//
#include <hip/hip_runtime.h>

// Pipeline (fp16-packed gathers, fp32 accum, MFMA node-GEMM, dst-sorted attention):
//   k_prep : blocks<64: W1 -> W1^T bf16 pre-swizzled; blocks>=64: zero denom+counts
//   k_gemm : blocks<gemm_blocks: g=h@W1 (mfma) + hh fp16 copy; tail: hist + rank[e]
//   k_scanA: 256-block chunk reduce -> partials
//   k_scanC2: merged scanB+scanC (each block re-scans partials) -> row_start
//   k_fill0: bsrc[row_start[dst[e]] + rank[e]] = src[e]   (no atomics)
//   k_att2 : one dst per 16-lane sub (4 dst/wave); d-row in regs; 2 edges in flight;
//            DPP (VALU-pipe) 16-lane reduce instead of ds_swizzle shuffles;
//            bucket[j]=(s,att); denom[s]+=att
//   k_agg  : one dst per sub; broadcast bucket/denom loads; no shuffles; out stores

typedef unsigned int uint;
typedef unsigned short ushort;
typedef __attribute__((ext_vector_type(8))) short short8;
typedef __attribute__((ext_vector_type(4))) float f32x4;
typedef __attribute__((ext_vector_type(2))) _Float16 h2;

static __device__ __forceinline__ uint pack_f16(float a, float b) {
  _Float16 ha = (_Float16)a, hb = (_Float16)b;
  unsigned short ua = __builtin_bit_cast(unsigned short, ha);
  unsigned short ub = __builtin_bit_cast(unsigned short, hb);
  return ((uint)ub << 16) | ua;
}
static __device__ __forceinline__ float2 unpack_f16(uint u) {
  _Float16 lo = __builtin_bit_cast(_Float16, (unsigned short)(u & 0xffffu));
  _Float16 hi = __builtin_bit_cast(_Float16, (unsigned short)(u >> 16));
  return make_float2((float)lo, (float)hi);
}
static __device__ __forceinline__ h2 as_h2(uint u) { return __builtin_bit_cast(h2, u); }
static __device__ __forceinline__ h2 relu2(h2 a) {
  h2 r;
  r.x = a.x > (_Float16)0 ? a.x : (_Float16)0;
  r.y = a.y > (_Float16)0 ? a.y : (_Float16)0;
  return r;
}
static __device__ __forceinline__ float dot2acc(h2 a, h2 b, float c) {
#if __has_builtin(__builtin_amdgcn_fdot2)
  return __builtin_amdgcn_fdot2(a, b, c, false);
#else
  return c + (float)a.x * (float)b.x + (float)a.y * (float)b.y;
#endif
}
static __device__ __forceinline__ ushort f2bf(float x) {
  uint u = __float_as_uint(x);
  u += 0x7fffu + ((u >> 16) & 1u);   // RNE
  return (ushort)(u >> 16);
}
// 16-lane sum on the VALU pipe via DPP (quad_perm xor1, xor2, row_ror:4, row_ror:8).
// DPP "row" = 16 lanes = our sub-group, so no cross-sub leakage.
static __device__ __forceinline__ float dpp_red16(float x) {
  int v;
  v = __builtin_amdgcn_update_dpp(0, __builtin_bit_cast(int, x), 0xB1, 0xF, 0xF, true);
  x += __builtin_bit_cast(float, v);   // quad_perm [1,0,3,2]  (xor 1)
  v = __builtin_amdgcn_update_dpp(0, __builtin_bit_cast(int, x), 0x4E, 0xF, 0xF, true);
  x += __builtin_bit_cast(float, v);   // quad_perm [2,3,0,1]  (xor 2)
  v = __builtin_amdgcn_update_dpp(0, __builtin_bit_cast(int, x), 0x124, 0xF, 0xF, true);
  x += __builtin_bit_cast(float, v);   // row_ror:4
  v = __builtin_amdgcn_update_dpp(0, __builtin_bit_cast(int, x), 0x128, 0xF, 0xF, true);
  x += __builtin_bit_cast(float, v);   // row_ror:8
  return x;                            // every lane holds the 16-lane sum
}

// blocks 0..63: W1[k][n] fp32 -> W1^T bf16 swizzled; blocks 64+: zero denom+counts
__global__ __launch_bounds__(256) void k_prep(const float* __restrict__ W1,
                                              ushort* __restrict__ w1t_swz,
                                              int* __restrict__ zbase, int zwords) {
  int b = blockIdx.x;
  if (b < 64) {
    int idx = b * 256 + threadIdx.x;
    int n = idx >> 7, k = idx & 127;
    float v = W1[k * 128 + n];
    int byte_off = n * 256 + ((k * 2) ^ ((n & 7) << 4));
    w1t_swz[byte_off >> 1] = f2bf(v);
  } else {
    int i = (b - 64) * 256 + threadIdx.x;
    int stride = (gridDim.x - 64) * 256;
    for (; i < zwords; i += stride) zbase[i] = 0;
  }
}

__global__ __launch_bounds__(256) void k_gemm(const float* __restrict__ h,
                                              const ushort* __restrict__ w1t_swz,
                                              uint* __restrict__ gh,
                                              uint4* __restrict__ hh4,
                                              int n_nodes,
                                              const int* __restrict__ dst,
                                              int* __restrict__ counts,
                                              int* __restrict__ rank,
                                              int n_edges, int gemm_blocks) {
  if ((int)blockIdx.x >= gemm_blocks) {          // histogram + rank tail blocks
    int hb = blockIdx.x - gemm_blocks;
    int i = hb * 256 + threadIdx.x;
    int stride = (gridDim.x - gemm_blocks) * 256;
    for (int e = i; e < n_edges; e += stride) {
      int r = atomicAdd(&counts[dst[e]], 1);
      rank[e] = r;
    }
    return;
  }
  __shared__ ushort w1s[16384];   // 32 KiB swizzled W1^T image
  int tid = threadIdx.x;
  {
    const uint4* srcw = (const uint4*)w1t_swz;
    uint4* dstw = (uint4*)w1s;
    #pragma unroll
    for (int i = 0; i < 8; ++i) dstw[tid + 256 * i] = srcw[tid + 256 * i];
  }
  __syncthreads();
  int wave = tid >> 6, lane = tid & 63;
  int tile = blockIdx.x * 4 + wave;
  if (tile * 16 >= n_nodes) return;
  int n0 = tile * 16;
  int l15 = lane & 15, kq = lane >> 4;
  int row = n0 + l15;

  f32x4 acc[8];
  #pragma unroll
  for (int ct = 0; ct < 8; ++ct) acc[ct] = (f32x4){0.f, 0.f, 0.f, 0.f};

  #pragma unroll
  for (int kb = 0; kb < 4; ++kb) {
    const float* hp = &h[(size_t)row * 128 + kb * 32 + kq * 8];
    float4 p0 = *(const float4*)hp;
    float4 p1 = *(const float4*)(hp + 4);
    short8 a;
    a[0] = (short)f2bf(p0.x); a[1] = (short)f2bf(p0.y);
    a[2] = (short)f2bf(p0.z); a[3] = (short)f2bf(p0.w);
    a[4] = (short)f2bf(p1.x); a[5] = (short)f2bf(p1.y);
    a[6] = (short)f2bf(p1.z); a[7] = (short)f2bf(p1.w);
    uint4 hv;
    hv.x = pack_f16(p0.x, p0.y); hv.y = pack_f16(p0.z, p0.w);
    hv.z = pack_f16(p1.x, p1.y); hv.w = pack_f16(p1.z, p1.w);
    hh4[(size_t)row * 16 + kb * 4 + kq] = hv;
    #pragma unroll
    for (int ct = 0; ct < 8; ++ct) {
      int n = ct * 16 + l15;
      int byte_off = n * 256 + (((kb * 64) + kq * 16) ^ ((n & 7) << 4));
      short8 b = *(const short8*)((const char*)w1s + byte_off);
      acc[ct] = __builtin_amdgcn_mfma_f32_16x16x32_bf16(a, b, acc[ct], 0, 0, 0);
    }
  }
  ushort* gh16 = (ushort*)gh;
  #pragma unroll
  for (int ct = 0; ct < 8; ++ct) {
    #pragma unroll
    for (int r = 0; r < 4; ++r) {
      int orow = n0 + kq * 4 + r;
      _Float16 v = (_Float16)acc[ct][r];
      gh16[(size_t)orow * 128 + ct * 16 + l15] = __builtin_bit_cast(unsigned short, v);
    }
  }
}

__global__ __launch_bounds__(256) void k_scanA(const int* __restrict__ counts,
                                               int* __restrict__ partials,
                                               int n, int chunk) {
  __shared__ int red[256];
  int b = blockIdx.x, t = threadIdx.x;
  int idx = b * chunk + t;
  red[t] = (t < chunk && idx < n) ? counts[idx] : 0;
  __syncthreads();
  for (int off = 128; off > 0; off >>= 1) {
    if (t < off) red[t] += red[t + off];
    __syncthreads();
  }
  if (t == 0) partials[b] = red[0];
}

// merged scanB+scanC: each block re-scans the 256 partials to get its base
__global__ __launch_bounds__(256) void k_scanC2(const int* __restrict__ counts,
                                                const int* __restrict__ partials,
                                                int* __restrict__ row_start,
                                                int n, int chunk, int total) {
  __shared__ int bp[256];
  __shared__ int p[256];
  int b = blockIdx.x, t = threadIdx.x;
  bp[t] = partials[t];
  __syncthreads();
  #pragma unroll
  for (int off = 1; off < 256; off <<= 1) {
    int v = (t >= off) ? bp[t - off] : 0;
    __syncthreads();
    bp[t] += v;
    __syncthreads();
  }
  int base = (b == 0) ? 0 : bp[b - 1];
  int idx = b * chunk + t;
  bool ok = (t < chunk && idx < n);
  int orig = ok ? counts[idx] : 0;
  p[t] = orig;
  __syncthreads();
  #pragma unroll
  for (int off = 1; off < 256; off <<= 1) {
    int v = (t >= off) ? p[t - off] : 0;
    __syncthreads();
    p[t] += v;
    __syncthreads();
  }
  if (ok) row_start[idx] = base + p[t] - orig;
  if (b == 0 && t == 0) row_start[n] = total;
}

__global__ __launch_bounds__(256) void k_fill0(const int* __restrict__ src,
                                               const int* __restrict__ dst,
                                               const int* __restrict__ row_start,
                                               const int* __restrict__ rank,
                                               int* __restrict__ bsrc,
                                               int n_edges) {
  int i = blockIdx.x * blockDim.x + threadIdx.x;
  int stride = gridDim.x * blockDim.x;
  for (int e = i; e < n_edges; e += stride) {
    bsrc[row_start[dst[e]] + rank[e]] = src[e];
  }
}

// one dst per 16-lane sub (4 dst/wave); d-row in regs; 2 edges in flight per sub
__global__ __launch_bounds__(256) void k_att2(const uint4* __restrict__ gh4,
                                              const int* __restrict__ bsrc,
                                              const int* __restrict__ row_start,
                                              const float* __restrict__ b1,
                                              const float* __restrict__ W2,
                                              const float* __restrict__ b2,
                                              int2* __restrict__ bucket,
                                              float* __restrict__ denom,
                                              int n_nodes) {
  int lane = threadIdx.x & 63;
  int sub = lane >> 4, l16 = lane & 15;
  int wavei = threadIdx.x >> 6;
  int d = blockIdx.x * 16 + wavei * 4 + sub;
  int beg = 0, end = 0;
  if (d < n_nodes) { beg = row_start[d]; end = row_start[d + 1]; }
  float4 b1a = *(const float4*)&b1[l16 * 8];
  float4 b1b = *(const float4*)&b1[l16 * 8 + 4];
  float4 w2a = *(const float4*)&W2[l16 * 8];
  float4 w2b = *(const float4*)&W2[l16 * 8 + 4];
  float b2v = b2[0];
  h2 c0, c1, c2, c3, wh0, wh1, wh2, wh3;
  wh0.x = (_Float16)w2a.x; wh0.y = (_Float16)w2a.y;
  wh1.x = (_Float16)w2a.z; wh1.y = (_Float16)w2a.w;
  wh2.x = (_Float16)w2b.x; wh2.y = (_Float16)w2b.y;
  wh3.x = (_Float16)w2b.z; wh3.y = (_Float16)w2b.w;
  c0 = (h2)(_Float16)0; c1 = c0; c2 = c0; c3 = c0;
  if (beg < end) {
    uint4 ud = gh4[(size_t)d * 16 + l16];
    float2 d0 = unpack_f16(ud.x), d1 = unpack_f16(ud.y);
    float2 d2 = unpack_f16(ud.z), d3 = unpack_f16(ud.w);
    c0.x = (_Float16)(b1a.x - d0.x); c0.y = (_Float16)(b1a.y - d0.y);
    c1.x = (_Float16)(b1a.z - d1.x); c1.y = (_Float16)(b1a.w - d1.y);
    c2.x = (_Float16)(b1b.x - d2.x); c2.y = (_Float16)(b1b.y - d2.y);
    c3.x = (_Float16)(b1b.z - d3.x); c3.y = (_Float16)(b1b.w - d3.y);
  }
  for (int j0 = beg; j0 < end; j0 += 2) {
    int j1 = j0 + 1;
    bool v1 = j1 < end;
    int s0 = bsrc[j0];
    int s1 = v1 ? bsrc[j1] : 0;
    uint4 ua = gh4[(size_t)s0 * 16 + l16];
    uint4 ub;
    if (v1) ub = gh4[(size_t)s1 * 16 + l16];
    float acc0 = 0.f, acc1 = 0.f;
    acc0 = dot2acc(relu2(as_h2(ua.x) + c0), wh0, acc0);
    acc0 = dot2acc(relu2(as_h2(ua.y) + c1), wh1, acc0);
    acc0 = dot2acc(relu2(as_h2(ua.z) + c2), wh2, acc0);
    acc0 = dot2acc(relu2(as_h2(ua.w) + c3), wh3, acc0);
    if (v1) {
      acc1 = dot2acc(relu2(as_h2(ub.x) + c0), wh0, acc1);
      acc1 = dot2acc(relu2(as_h2(ub.y) + c1), wh1, acc1);
      acc1 = dot2acc(relu2(as_h2(ub.z) + c2), wh2, acc1);
      acc1 = dot2acc(relu2(as_h2(ub.w) + c3), wh3, acc1);
    }
    // VALU-pipe reduce (DPP), no DS ops
    acc0 = dpp_red16(acc0);
    acc1 = dpp_red16(acc1);
    if (l16 == 0) {
      float a = fmaxf(acc0 + b2v, 0.f);
      a = 1.f / (1.f + __expf(-a));
      bucket[j0] = make_int2(s0, __float_as_int(a));
      atomicAdd(&denom[s0], a);
      if (v1) {
        float a1 = fmaxf(acc1 + b2v, 0.f);
        a1 = 1.f / (1.f + __expf(-a1));
        bucket[j1] = make_int2(s1, __float_as_int(a1));
        atomicAdd(&denom[s1], a1);
      }
    }
  }
}

// one dst per sub; broadcast bucket/denom loads; no shuffles
__global__ __launch_bounds__(256) void k_agg(const uint4* __restrict__ hh4,
                                             const int* __restrict__ row_start,
                                             const int2* __restrict__ bucket,
                                             const float* __restrict__ denom,
                                             float* __restrict__ out, int n_nodes) {
  int lane = threadIdx.x & 63;
  int sub = lane >> 4, l16 = lane & 15;
  int wavei = threadIdx.x >> 6;
  int d = blockIdx.x * 16 + wavei * 4 + sub;
  int beg = 0, end = 0;
  if (d < n_nodes) { beg = row_start[d]; end = row_start[d + 1]; }
  float a0 = 0.f, a1 = 0.f, a2 = 0.f, a3 = 0.f;
  float a4 = 0.f, a5 = 0.f, a6 = 0.f, a7 = 0.f;
  for (int j0 = beg; j0 < end; j0 += 2) {
    int j1 = j0 + 1;
    bool v1 = j1 < end;
    int2 e0 = bucket[j0];
    int2 e1 = v1 ? bucket[j1] : make_int2(0, 0);
    float w0 = __int_as_float(e0.y) / denom[e0.x];
    float w1 = v1 ? __int_as_float(e1.y) / denom[e1.x] : 0.f;
    uint4 va = hh4[(size_t)e0.x * 16 + l16];
    uint4 vb;
    if (v1) vb = hh4[(size_t)e1.x * 16 + l16];
    {
      float2 f0 = unpack_f16(va.x), f1 = unpack_f16(va.y);
      float2 f2 = unpack_f16(va.z), f3 = unpack_f16(va.w);
      a0 = fmaf(w0, f0.x, a0); a1 = fmaf(w0, f0.y, a1);
      a2 = fmaf(w0, f1.x, a2); a3 = fmaf(w0, f1.y, a3);
      a4 = fmaf(w0, f2.x, a4); a5 = fmaf(w0, f2.y, a5);
      a6 = fmaf(w0, f3.x, a6); a7 = fmaf(w0, f3.y, a7);
    }
    if (v1) {
      float2 f0 = unpack_f16(vb.x), f1 = unpack_f16(vb.y);
      float2 f2 = unpack_f16(vb.z), f3 = unpack_f16(vb.w);
      a0 = fmaf(w1, f0.x, a0); a1 = fmaf(w1, f0.y, a1);
      a2 = fmaf(w1, f1.x, a2); a3 = fmaf(w1, f1.y, a3);
      a4 = fmaf(w1, f2.x, a4); a5 = fmaf(w1, f2.y, a5);
      a6 = fmaf(w1, f3.x, a6); a7 = fmaf(w1, f3.y, a7);
    }
  }
  if (d < n_nodes) {
    *(float4*)&out[(size_t)d * 128 + l16 * 8]     = make_float4(a0, a1, a2, a3);
    *(float4*)&out[(size_t)d * 128 + l16 * 8 + 4] = make_float4(a4, a5, a6, a7);
  }
}

extern "C" void kernel_launch(void* const* d_in, const int* in_sizes, int n_in,
                              void* d_out, int out_size, void* d_ws, size_t ws_size,
                              hipStream_t stream) {
  const float* h   = (const float*)d_in[0];
  const int*   src = (const int*)d_in[1];
  const int*   dst = (const int*)d_in[2];
  const float* W1  = (const float*)d_in[3];
  const float* b1  = (const float*)d_in[4];
  const float* W2  = (const float*)d_in[5];
  const float* b2  = (const float*)d_in[6];
  float* out = (float*)d_out;

  int n_nodes = in_sizes[0] / 128;
  int n_edges = in_sizes[1];

  char* ws = (char*)d_ws;
  uint*   gh        = (uint*)ws;                            // n*64
  uint*   hh        = gh + (size_t)n_nodes * 64;            // n*64
  float*  denom     = (float*)(hh + (size_t)n_nodes * 64);  // n
  int*    counts    = (int*)(denom + n_nodes);              // n
  int*    row_start = counts + n_nodes;                     // n+1
  int*    partials  = row_start + n_nodes + 1;              // 256
  ushort* w1t       = (ushort*)(partials + 256);            // 16384 (32 KiB)
  int*    bsrc      = (int*)(w1t + 16384);                  // E
  int*    rank      = bsrc + n_edges;                       // E
  int2*   bucket    = (int2*)(((uintptr_t)(rank + n_edges) + 15) & ~(uintptr_t)15);

  int chunk = (n_nodes + 255) / 256;
  int n_tiles = (n_nodes + 15) / 16;
  int gemm_blocks = (n_tiles + 3) / 4;
  int nblk16 = (n_nodes + 15) / 16;
  k_prep  <<<64 + 16, 256, 0, stream>>>(W1, w1t, (int*)denom, 2 * n_nodes);
  k_gemm  <<<gemm_blocks + 256, 256, 0, stream>>>(h, w1t, gh, (uint4*)hh, n_nodes,
                                                  dst, counts, rank, n_edges, gemm_blocks);
  k_scanA <<<256, 256, 0, stream>>>(counts, partials, n_nodes, chunk);
  k_scanC2<<<256, 256, 0, stream>>>(counts, partials, row_start, n_nodes, chunk, n_edges);
  k_fill0 <<<1024, 256, 0, stream>>>(src, dst, row_start, rank, bsrc, n_edges);
  k_att2  <<<nblk16, 256, 0, stream>>>((const uint4*)gh, bsrc, row_start, b1, W2, b2,
                                       bucket, denom, n_nodes);
  k_agg   <<<nblk16, 256, 0, stream>>>((const uint4*)hh, row_start, bucket, denom, out, n_nodes);
}

// Round 12
// 133.955 us; speedup vs baseline: 1.2415x; 1.0080x over previous
//
#include <hip/hip_runtime.h>
#include <hip/hip_fp8.h>

// Pipeline (fp8 attention table, fp16 agg table, fp32 accum, MFMA node-GEMM):
//   k_prep : blocks<64: W1 -> W1^T bf16 pre-swizzled; blocks>=64: zero denom+counts
//   k_gemm : blocks<gemm_blocks: g=h@W1 (mfma) -> gh8 (fp8 e4m3, 128B rows)
//            + hh fp16 copy (256B rows); tail: hist + rank[e]
//   k_scanA: 256-block chunk reduce -> partials
//   k_scanC2: merged scan -> row_start
//   k_fill0: bsrc[row_start[dst[e]] + rank[e]] = src[e]   (no atomics)
//   k_att2 : one dst per 16-lane sub; d-row in regs; 1 fp8 gather (8B/lane)/edge,
//            2 edges in flight; DPP reduce; bucket[j]=(s,att); denom[s]+=att
//   k_agg  : one dst per sub; broadcast bucket/denom; fp16 gathers; out stores

typedef unsigned int uint;
typedef unsigned short ushort;
typedef unsigned char uchar;
typedef __attribute__((ext_vector_type(8))) short short8;
typedef __attribute__((ext_vector_type(4))) float f32x4;
typedef __attribute__((ext_vector_type(2))) float f32x2;

static __device__ __forceinline__ uint pack_f16(float a, float b) {
  _Float16 ha = (_Float16)a, hb = (_Float16)b;
  unsigned short ua = __builtin_bit_cast(unsigned short, ha);
  unsigned short ub = __builtin_bit_cast(unsigned short, hb);
  return ((uint)ub << 16) | ua;
}
static __device__ __forceinline__ float2 unpack_f16(uint u) {
  _Float16 lo = __builtin_bit_cast(_Float16, (unsigned short)(u & 0xffffu));
  _Float16 hi = __builtin_bit_cast(_Float16, (unsigned short)(u >> 16));
  return make_float2((float)lo, (float)hi);
}
static __device__ __forceinline__ ushort f2bf(float x) {
  uint u = __float_as_uint(x);
  u += 0x7fffu + ((u >> 16) & 1u);   // RNE
  return (ushort)(u >> 16);
}

// ---- fp8 e4m3 helpers (hi selector must be an IMMEDIATE -> template param) ----
#if __has_builtin(__builtin_amdgcn_cvt_pk_fp8_f32) && __has_builtin(__builtin_amdgcn_cvt_pk_f32_fp8)
static __device__ __forceinline__ uchar f2fp8(float v) {
  uint u = __builtin_amdgcn_cvt_pk_fp8_f32(v, v, 0u, false);
  return (uchar)(u & 0xFFu);
}
template <bool HI>
static __device__ __forceinline__ float2 fp8x2(uint word) {
  f32x2 r = __builtin_amdgcn_cvt_pk_f32_fp8(word, HI);
  return make_float2(r.x, r.y);
}
#else
static __device__ __forceinline__ uchar f2fp8(float v) {
  __hip_fp8_e4m3 t(v);
  return *(uchar*)&t;
}
static __device__ __forceinline__ float fp8one(uchar b) {
  __hip_fp8_e4m3 t;
  *(uchar*)&t = b;
  return (float)t;
}
template <bool HI>
static __device__ __forceinline__ float2 fp8x2(uint word) {
  uint sh = HI ? 16 : 0;
  return make_float2(fp8one((uchar)(word >> sh)), fp8one((uchar)(word >> (sh + 8))));
}
#endif

// 16-lane sum on the VALU pipe via DPP; row (16 lanes) == sub-group.
static __device__ __forceinline__ float dpp_red16(float x) {
  int v;
  v = __builtin_amdgcn_update_dpp(0, __builtin_bit_cast(int, x), 0xB1, 0xF, 0xF, true);
  x += __builtin_bit_cast(float, v);   // quad_perm xor1
  v = __builtin_amdgcn_update_dpp(0, __builtin_bit_cast(int, x), 0x4E, 0xF, 0xF, true);
  x += __builtin_bit_cast(float, v);   // quad_perm xor2
  v = __builtin_amdgcn_update_dpp(0, __builtin_bit_cast(int, x), 0x124, 0xF, 0xF, true);
  x += __builtin_bit_cast(float, v);   // row_ror:4
  v = __builtin_amdgcn_update_dpp(0, __builtin_bit_cast(int, x), 0x128, 0xF, 0xF, true);
  x += __builtin_bit_cast(float, v);   // row_ror:8
  return x;
}

// blocks 0..63: W1 -> W1^T bf16 swizzled; blocks 64+: zero denom+counts
__global__ __launch_bounds__(256) void k_prep(const float* __restrict__ W1,
                                              ushort* __restrict__ w1t_swz,
                                              int* __restrict__ zbase, int zwords) {
  int b = blockIdx.x;
  if (b < 64) {
    int idx = b * 256 + threadIdx.x;
    int n = idx >> 7, k = idx & 127;
    float v = W1[k * 128 + n];
    int byte_off = n * 256 + ((k * 2) ^ ((n & 7) << 4));
    w1t_swz[byte_off >> 1] = f2bf(v);
  } else {
    int i = (b - 64) * 256 + threadIdx.x;
    int stride = (gridDim.x - 64) * 256;
    for (; i < zwords; i += stride) zbase[i] = 0;
  }
}

__global__ __launch_bounds__(256) void k_gemm(const float* __restrict__ h,
                                              const ushort* __restrict__ w1t_swz,
                                              uchar* __restrict__ gh8,
                                              uint4* __restrict__ hh4,
                                              int n_nodes,
                                              const int* __restrict__ dst,
                                              int* __restrict__ counts,
                                              int* __restrict__ rank,
                                              int n_edges, int gemm_blocks) {
  if ((int)blockIdx.x >= gemm_blocks) {          // histogram + rank tail blocks
    int hb = blockIdx.x - gemm_blocks;
    int i = hb * 256 + threadIdx.x;
    int stride = (gridDim.x - gemm_blocks) * 256;
    for (int e = i; e < n_edges; e += stride) {
      int r = atomicAdd(&counts[dst[e]], 1);
      rank[e] = r;
    }
    return;
  }
  __shared__ ushort w1s[16384];   // 32 KiB swizzled W1^T image
  int tid = threadIdx.x;
  {
    const uint4* srcw = (const uint4*)w1t_swz;
    uint4* dstw = (uint4*)w1s;
    #pragma unroll
    for (int i = 0; i < 8; ++i) dstw[tid + 256 * i] = srcw[tid + 256 * i];
  }
  __syncthreads();
  int wave = tid >> 6, lane = tid & 63;
  int tile = blockIdx.x * 4 + wave;
  if (tile * 16 >= n_nodes) return;
  int n0 = tile * 16;
  int l15 = lane & 15, kq = lane >> 4;
  int row = n0 + l15;

  f32x4 acc[8];
  #pragma unroll
  for (int ct = 0; ct < 8; ++ct) acc[ct] = (f32x4){0.f, 0.f, 0.f, 0.f};

  #pragma unroll
  for (int kb = 0; kb < 4; ++kb) {
    const float* hp = &h[(size_t)row * 128 + kb * 32 + kq * 8];
    float4 p0 = *(const float4*)hp;
    float4 p1 = *(const float4*)(hp + 4);
    short8 a;
    a[0] = (short)f2bf(p0.x); a[1] = (short)f2bf(p0.y);
    a[2] = (short)f2bf(p0.z); a[3] = (short)f2bf(p0.w);
    a[4] = (short)f2bf(p1.x); a[5] = (short)f2bf(p1.y);
    a[6] = (short)f2bf(p1.z); a[7] = (short)f2bf(p1.w);
    uint4 hv;
    hv.x = pack_f16(p0.x, p0.y); hv.y = pack_f16(p0.z, p0.w);
    hv.z = pack_f16(p1.x, p1.y); hv.w = pack_f16(p1.z, p1.w);
    hh4[(size_t)row * 16 + kb * 4 + kq] = hv;
    #pragma unroll
    for (int ct = 0; ct < 8; ++ct) {
      int n = ct * 16 + l15;
      int byte_off = n * 256 + (((kb * 64) + kq * 16) ^ ((n & 7) << 4));
      short8 b = *(const short8*)((const char*)w1s + byte_off);
      acc[ct] = __builtin_amdgcn_mfma_f32_16x16x32_bf16(a, b, acc[ct], 0, 0, 0);
    }
  }
  // C/D: col = lane&15 (within ct tile), row = kq*4 + r
  #pragma unroll
  for (int ct = 0; ct < 8; ++ct) {
    #pragma unroll
    for (int r = 0; r < 4; ++r) {
      int orow = n0 + kq * 4 + r;
      gh8[(size_t)orow * 128 + ct * 16 + l15] = f2fp8(acc[ct][r]);
    }
  }
}

__global__ __launch_bounds__(256) void k_scanA(const int* __restrict__ counts,
                                               int* __restrict__ partials,
                                               int n, int chunk) {
  __shared__ int red[256];
  int b = blockIdx.x, t = threadIdx.x;
  int idx = b * chunk + t;
  red[t] = (t < chunk && idx < n) ? counts[idx] : 0;
  __syncthreads();
  for (int off = 128; off > 0; off >>= 1) {
    if (t < off) red[t] += red[t + off];
    __syncthreads();
  }
  if (t == 0) partials[b] = red[0];
}

__global__ __launch_bounds__(256) void k_scanC2(const int* __restrict__ counts,
                                                const int* __restrict__ partials,
                                                int* __restrict__ row_start,
                                                int n, int chunk, int total) {
  __shared__ int bp[256];
  __shared__ int p[256];
  int b = blockIdx.x, t = threadIdx.x;
  bp[t] = partials[t];
  __syncthreads();
  #pragma unroll
  for (int off = 1; off < 256; off <<= 1) {
    int v = (t >= off) ? bp[t - off] : 0;
    __syncthreads();
    bp[t] += v;
    __syncthreads();
  }
  int base = (b == 0) ? 0 : bp[b - 1];
  int idx = b * chunk + t;
  bool ok = (t < chunk && idx < n);
  int orig = ok ? counts[idx] : 0;
  p[t] = orig;
  __syncthreads();
  #pragma unroll
  for (int off = 1; off < 256; off <<= 1) {
    int v = (t >= off) ? p[t - off] : 0;
    __syncthreads();
    p[t] += v;
    __syncthreads();
  }
  if (ok) row_start[idx] = base + p[t] - orig;
  if (b == 0 && t == 0) row_start[n] = total;
}

__global__ __launch_bounds__(256) void k_fill0(const int* __restrict__ src,
                                               const int* __restrict__ dst,
                                               const int* __restrict__ row_start,
                                               const int* __restrict__ rank,
                                               int* __restrict__ bsrc,
                                               int n_edges) {
  int i = blockIdx.x * blockDim.x + threadIdx.x;
  int stride = gridDim.x * blockDim.x;
  for (int e = i; e < n_edges; e += stride) {
    bsrc[row_start[dst[e]] + rank[e]] = src[e];
  }
}

// one dst per 16-lane sub (4 dst/wave); d-row in regs; 2 fp8 edges in flight
__global__ __launch_bounds__(256) void k_att2(const uint2* __restrict__ gh8v,
                                              const int* __restrict__ bsrc,
                                              const int* __restrict__ row_start,
                                              const float* __restrict__ b1,
                                              const float* __restrict__ W2,
                                              const float* __restrict__ b2,
                                              int2* __restrict__ bucket,
                                              float* __restrict__ denom,
                                              int n_nodes) {
  int lane = threadIdx.x & 63;
  int sub = lane >> 4, l16 = lane & 15;
  int wavei = threadIdx.x >> 6;
  int d = blockIdx.x * 16 + wavei * 4 + sub;
  int beg = 0, end = 0;
  if (d < n_nodes) { beg = row_start[d]; end = row_start[d + 1]; }
  float4 b1a = *(const float4*)&b1[l16 * 8];
  float4 b1b = *(const float4*)&b1[l16 * 8 + 4];
  float4 w2a = *(const float4*)&W2[l16 * 8];
  float4 w2b = *(const float4*)&W2[l16 * 8 + 4];
  float b2v = b2[0];
  float c0 = 0.f, c1 = 0.f, c2 = 0.f, c3 = 0.f;
  float c4 = 0.f, c5 = 0.f, c6 = 0.f, c7 = 0.f;
  if (beg < end) {
    uint2 ud = gh8v[(size_t)d * 16 + l16];
    float2 da = fp8x2<false>(ud.x), db = fp8x2<true>(ud.x);
    float2 dc = fp8x2<false>(ud.y), dd = fp8x2<true>(ud.y);
    c0 = b1a.x - da.x; c1 = b1a.y - da.y; c2 = b1a.z - db.x; c3 = b1a.w - db.y;
    c4 = b1b.x - dc.x; c5 = b1b.y - dc.y; c6 = b1b.z - dd.x; c7 = b1b.w - dd.y;
  }
  for (int j0 = beg; j0 < end; j0 += 2) {
    int j1 = j0 + 1;
    bool v1 = j1 < end;
    int s0 = bsrc[j0];
    int s1 = v1 ? bsrc[j1] : 0;
    uint2 ua = gh8v[(size_t)s0 * 16 + l16];
    uint2 ub;
    if (v1) ub = gh8v[(size_t)s1 * 16 + l16];
    float acc0 = 0.f, acc1 = 0.f;
    {
      float2 f0 = fp8x2<false>(ua.x), f1 = fp8x2<true>(ua.x);
      float2 f2 = fp8x2<false>(ua.y), f3 = fp8x2<true>(ua.y);
      float t;
      t = fmaxf(f0.x + c0, 0.f); acc0 = fmaf(t, w2a.x, acc0);
      t = fmaxf(f0.y + c1, 0.f); acc0 = fmaf(t, w2a.y, acc0);
      t = fmaxf(f1.x + c2, 0.f); acc0 = fmaf(t, w2a.z, acc0);
      t = fmaxf(f1.y + c3, 0.f); acc0 = fmaf(t, w2a.w, acc0);
      t = fmaxf(f2.x + c4, 0.f); acc0 = fmaf(t, w2b.x, acc0);
      t = fmaxf(f2.y + c5, 0.f); acc0 = fmaf(t, w2b.y, acc0);
      t = fmaxf(f3.x + c6, 0.f); acc0 = fmaf(t, w2b.z, acc0);
      t = fmaxf(f3.y + c7, 0.f); acc0 = fmaf(t, w2b.w, acc0);
    }
    if (v1) {
      float2 f0 = fp8x2<false>(ub.x), f1 = fp8x2<true>(ub.x);
      float2 f2 = fp8x2<false>(ub.y), f3 = fp8x2<true>(ub.y);
      float t;
      t = fmaxf(f0.x + c0, 0.f); acc1 = fmaf(t, w2a.x, acc1);
      t = fmaxf(f0.y + c1, 0.f); acc1 = fmaf(t, w2a.y, acc1);
      t = fmaxf(f1.x + c2, 0.f); acc1 = fmaf(t, w2a.z, acc1);
      t = fmaxf(f1.y + c3, 0.f); acc1 = fmaf(t, w2a.w, acc1);
      t = fmaxf(f2.x + c4, 0.f); acc1 = fmaf(t, w2b.x, acc1);
      t = fmaxf(f2.y + c5, 0.f); acc1 = fmaf(t, w2b.y, acc1);
      t = fmaxf(f3.x + c6, 0.f); acc1 = fmaf(t, w2b.z, acc1);
      t = fmaxf(f3.y + c7, 0.f); acc1 = fmaf(t, w2b.w, acc1);
    }
    acc0 = dpp_red16(acc0);
    acc1 = dpp_red16(acc1);
    if (l16 == 0) {
      float a = fmaxf(acc0 + b2v, 0.f);
      a = 1.f / (1.f + __expf(-a));
      bucket[j0] = make_int2(s0, __float_as_int(a));
      atomicAdd(&denom[s0], a);
      if (v1) {
        float a1 = fmaxf(acc1 + b2v, 0.f);
        a1 = 1.f / (1.f + __expf(-a1));
        bucket[j1] = make_int2(s1, __float_as_int(a1));
        atomicAdd(&denom[s1], a1);
      }
    }
  }
}

// one dst per sub; broadcast bucket/denom loads; fp16 row gathers
__global__ __launch_bounds__(256) void k_agg(const uint4* __restrict__ hh4,
                                             const int* __restrict__ row_start,
                                             const int2* __restrict__ bucket,
                                             const float* __restrict__ denom,
                                             float* __restrict__ out, int n_nodes) {
  int lane = threadIdx.x & 63;
  int sub = lane >> 4, l16 = lane & 15;
  int wavei = threadIdx.x >> 6;
  int d = blockIdx.x * 16 + wavei * 4 + sub;
  int beg = 0, end = 0;
  if (d < n_nodes) { beg = row_start[d]; end = row_start[d + 1]; }
  float a0 = 0.f, a1 = 0.f, a2 = 0.f, a3 = 0.f;
  float a4 = 0.f, a5 = 0.f, a6 = 0.f, a7 = 0.f;
  for (int j0 = beg; j0 < end; j0 += 2) {
    int j1 = j0 + 1;
    bool v1 = j1 < end;
    int2 e0 = bucket[j0];
    int2 e1 = v1 ? bucket[j1] : make_int2(0, 0);
    float w0 = __int_as_float(e0.y) / denom[e0.x];
    float w1 = v1 ? __int_as_float(e1.y) / denom[e1.x] : 0.f;
    uint4 va = hh4[(size_t)e0.x * 16 + l16];
    uint4 vb;
    if (v1) vb = hh4[(size_t)e1.x * 16 + l16];
    {
      float2 f0 = unpack_f16(va.x), f1 = unpack_f16(va.y);
      float2 f2 = unpack_f16(va.z), f3 = unpack_f16(va.w);
      a0 = fmaf(w0, f0.x, a0); a1 = fmaf(w0, f0.y, a1);
      a2 = fmaf(w0, f1.x, a2); a3 = fmaf(w0, f1.y, a3);
      a4 = fmaf(w0, f2.x, a4); a5 = fmaf(w0, f2.y, a5);
      a6 = fmaf(w0, f3.x, a6); a7 = fmaf(w0, f3.y, a7);
    }
    if (v1) {
      float2 f0 = unpack_f16(vb.x), f1 = unpack_f16(vb.y);
      float2 f2 = unpack_f16(vb.z), f3 = unpack_f16(vb.w);
      a0 = fmaf(w1, f0.x, a0); a1 = fmaf(w1, f0.y, a1);
      a2 = fmaf(w1, f1.x, a2); a3 = fmaf(w1, f1.y, a3);
      a4 = fmaf(w1, f2.x, a4); a5 = fmaf(w1, f2.y, a5);
      a6 = fmaf(w1, f3.x, a6); a7 = fmaf(w1, f3.y, a7);
    }
  }
  if (d < n_nodes) {
    *(float4*)&out[(size_t)d * 128 + l16 * 8]     = make_float4(a0, a1, a2, a3);
    *(float4*)&out[(size_t)d * 128 + l16 * 8 + 4] = make_float4(a4, a5, a6, a7);
  }
}

extern "C" void kernel_launch(void* const* d_in, const int* in_sizes, int n_in,
                              void* d_out, int out_size, void* d_ws, size_t ws_size,
                              hipStream_t stream) {
  const float* h   = (const float*)d_in[0];
  const int*   src = (const int*)d_in[1];
  const int*   dst = (const int*)d_in[2];
  const float* W1  = (const float*)d_in[3];
  const float* b1  = (const float*)d_in[4];
  const float* W2  = (const float*)d_in[5];
  const float* b2  = (const float*)d_in[6];
  float* out = (float*)d_out;

  int n_nodes = in_sizes[0] / 128;
  int n_edges = in_sizes[1];

  char* ws = (char*)d_ws;
  uchar*  gh8       = (uchar*)ws;                           // n*128 bytes (fp8 rows)
  uint*   hh        = (uint*)(ws + (size_t)n_nodes * 128);  // n*64 uints (fp16 rows)
  float*  denom     = (float*)(hh + (size_t)n_nodes * 64);  // n
  int*    counts    = (int*)(denom + n_nodes);              // n
  int*    row_start = counts + n_nodes;                     // n+1
  int*    partials  = row_start + n_nodes + 1;              // 256
  ushort* w1t       = (ushort*)(partials + 256);            // 16384 (32 KiB)
  int*    bsrc      = (int*)(w1t + 16384);                  // E
  int*    rank      = bsrc + n_edges;                       // E
  int2*   bucket    = (int2*)(((uintptr_t)(rank + n_edges) + 15) & ~(uintptr_t)15);

  int chunk = (n_nodes + 255) / 256;
  int n_tiles = (n_nodes + 15) / 16;
  int gemm_blocks = (n_tiles + 3) / 4;
  int nblk16 = (n_nodes + 15) / 16;
  k_prep  <<<64 + 16, 256, 0, stream>>>(W1, w1t, (int*)denom, 2 * n_nodes);
  k_gemm  <<<gemm_blocks + 256, 256, 0, stream>>>(h, w1t, gh8, (uint4*)hh, n_nodes,
                                                  dst, counts, rank, n_edges, gemm_blocks);
  k_scanA <<<256, 256, 0, stream>>>(counts, partials, n_nodes, chunk);
  k_scanC2<<<256, 256, 0, stream>>>(counts, partials, row_start, n_nodes, chunk, n_edges);
  k_fill0 <<<1024, 256, 0, stream>>>(src, dst, row_start, rank, bsrc, n_edges);
  k_att2  <<<nblk16, 256, 0, stream>>>((const uint2*)gh8, bsrc, row_start, b1, W2, b2,
                                       bucket, denom, n_nodes);
  k_agg   <<<nblk16, 256, 0, stream>>>((const uint4*)hh, row_start, bucket, denom, out, n_nodes);
}